// Round 1
// baseline (1302.028 us; speedup 1.0000x reference)
//
#include <hip/hip_runtime.h>
#include <math.h>

#define BB 8
#define LL 1024
#define DD 768
#define NNs 16
#define RR 48

__device__ __forceinline__ float silu_f(float v) { return v / (1.0f + __expf(-v)); }

// ---------------------------------------------------------------------------
// K1: pos embedding (analytic) + residual + RMSNorm. One block per (b,l) row.
// ---------------------------------------------------------------------------
__global__ __launch_bounds__(256) void k_pos_rms(const float* __restrict__ x,
                                                 const float* __restrict__ norm_w,
                                                 float* __restrict__ res,
                                                 float* __restrict__ hid) {
    int row = blockIdx.x;            // b*L + l
    int l = row & (LL - 1);
    int d3 = l & 3;
    int w = (l >> 2) & 15;
    int h = l >> 6;
    float coord[3] = { h * (1.0f / 15.0f), w * (1.0f / 15.0f), d3 * (1.0f / 3.0f) };
    const float LOG1E4 = 9.210340371976184f;   // ln(10000)
    int t = threadIdx.x;
    float r[3];
    float s = 0.0f;
#pragma unroll
    for (int i = 0; i < 3; i++) {
        int j = t + i * 256;
        int c = j >> 8;              // channel 0..2
        int fp = j & 255;
        int f = fp & 127;
        float omega = __expf(-(f * (1.0f / 128.0f)) * LOG1E4);
        float arg = coord[c] * omega;
        float pv = (fp < 128) ? __sinf(arg) : __cosf(arg);
        float rv = x[(size_t)row * DD + j] + pv;
        r[i] = rv;
        s += rv * rv;
    }
    // reduce over 256 threads: wave64 shuffle + LDS
#pragma unroll
    for (int off = 32; off; off >>= 1) s += __shfl_xor(s, off, 64);
    __shared__ float ls[4];
    if ((t & 63) == 0) ls[t >> 6] = s;
    __syncthreads();
    s = ls[0] + ls[1] + ls[2] + ls[3];
    float rs = rsqrtf(s * (1.0f / DD) + 1e-5f);
#pragma unroll
    for (int i = 0; i < 3; i++) {
        int j = t + i * 256;
        res[(size_t)row * DD + j] = r[i];
        hid[(size_t)row * DD + j] = r[i] * rs * norm_w[j];
    }
}

// ---------------------------------------------------------------------------
// Generic NT GEMM: C[m][n] = sum_k A[m][k] * Bw[n][k] (+bias) with epilogues.
// BM=BN=64, BK=16, 256 threads, 4x4 per thread. M assumed multiple of 64.
// MODE 0: plain store (bias optional)      MODE 1: split write (xz -> xin|z)
// MODE 2: softplus                         MODE 3: + residual
// ---------------------------------------------------------------------------
template <int MODE>
__global__ __launch_bounds__(256) void gemm_nt(const float* __restrict__ A, int lda,
                                               const float* __restrict__ Bw, int ldb,
                                               int M, int N, int Kd,
                                               const float* __restrict__ bias,
                                               const float* __restrict__ resid,
                                               float* __restrict__ C0,
                                               float* __restrict__ C1, int ldc) {
    __shared__ __align__(16) float As[16][68];
    __shared__ __align__(16) float Bs[16][68];
    int m0 = blockIdx.y * 64;
    int n0 = blockIdx.x * 64;
    int t = threadIdx.x;
    int tx = t & 15, ty = t >> 4;
    int ar = t >> 2;           // 0..63 tile row
    int ak = (t & 3) * 4;      // 0,4,8,12
    float acc[4][4] = {};
    for (int k0 = 0; k0 < Kd; k0 += 16) {
        float4 av = *(const float4*)(A + (size_t)(m0 + ar) * lda + k0 + ak);
        int brow = n0 + ar;
        if (brow >= N) brow = N - 1;
        float4 bv = *(const float4*)(Bw + (size_t)brow * ldb + k0 + ak);
        As[ak + 0][ar] = av.x; As[ak + 1][ar] = av.y;
        As[ak + 2][ar] = av.z; As[ak + 3][ar] = av.w;
        Bs[ak + 0][ar] = bv.x; Bs[ak + 1][ar] = bv.y;
        Bs[ak + 2][ar] = bv.z; Bs[ak + 3][ar] = bv.w;
        __syncthreads();
#pragma unroll
        for (int kk = 0; kk < 16; kk++) {
            float4 a4 = *(const float4*)&As[kk][ty * 4];
            float4 b4 = *(const float4*)&Bs[kk][tx * 4];
            float aa[4] = { a4.x, a4.y, a4.z, a4.w };
            float bb[4] = { b4.x, b4.y, b4.z, b4.w };
#pragma unroll
            for (int i = 0; i < 4; i++)
#pragma unroll
                for (int j = 0; j < 4; j++) acc[i][j] += aa[i] * bb[j];
        }
        __syncthreads();
    }
#pragma unroll
    for (int i = 0; i < 4; i++) {
        int m = m0 + ty * 4 + i;
#pragma unroll
        for (int j = 0; j < 4; j++) {
            int n = n0 + tx * 4 + j;
            if (n >= N) continue;
            float v = acc[i][j] + (bias ? bias[n] : 0.0f);
            if (MODE == 0) {
                C0[(size_t)m * ldc + n] = v;
            } else if (MODE == 1) {
                if (n < DD) C0[(size_t)m * DD + n] = v;
                else        C1[(size_t)m * DD + (n - DD)] = v;
            } else if (MODE == 2) {
                C0[(size_t)m * ldc + n] = (v > 20.0f) ? v : log1pf(__expf(v));
            } else {  // MODE 3
                C0[(size_t)m * ldc + n] = v + resid[(size_t)m * DD + n];
            }
        }
    }
}

// ---------------------------------------------------------------------------
// K3: depthwise causal conv (K=4) + bias + silu
// ---------------------------------------------------------------------------
__global__ __launch_bounds__(256) void k_conv(const float* __restrict__ xin,
                                              const float* __restrict__ cw,
                                              const float* __restrict__ cb,
                                              float* __restrict__ xc) {
    size_t gid = (size_t)blockIdx.x * 256 + threadIdx.x;
    int d = (int)(gid % DD);
    int bt = (int)(gid / DD);        // b*L + t
    int tt = bt & (LL - 1);
    float4 w = ((const float4*)cw)[d];   // conv_w[d,0,0..3]
    const float* p = xin + (size_t)bt * DD + d;
    float acc = cb[d];
    if (tt >= 3) acc += p[-3 * DD] * w.x;
    if (tt >= 2) acc += p[-2 * DD] * w.y;
    if (tt >= 1) acc += p[-1 * DD] * w.z;
    acc += p[0] * w.w;
    xc[gid] = silu_f(acc);
}

// ---------------------------------------------------------------------------
// K5: selective scan, fused dA/dBx/gating. 16 lanes per (b,d), n = lane%16.
// Writes y in-place into the z buffer.
// ---------------------------------------------------------------------------
__global__ __launch_bounds__(256) void k_scan(const float* __restrict__ dt,
                                              const float* __restrict__ xc,
                                              const float* __restrict__ xdbl,
                                              const float* __restrict__ A_log,
                                              const float* __restrict__ Dp,
                                              float* __restrict__ zy) {
    int tid = blockIdx.x * 256 + threadIdx.x;
    int n = tid & 15;
    int pair = tid >> 4;             // b*768 + d
    int b = pair / DD;
    int d = pair % DD;
    float Acoef = -__expf(A_log[d * NNs + n]);
    float Dv = Dp[d];
    float h = 0.0f;
    const float* dtp = dt + (size_t)b * LL * DD + d;
    const float* xcp = xc + (size_t)b * LL * DD + d;
    const float* xdp = xdbl + (size_t)b * LL * 80;
    float* zp = zy + (size_t)b * LL * DD + d;
    for (int t = 0; t < LL; t++) {
        float dtv = dtp[(size_t)t * DD];
        float xcv = xcp[(size_t)t * DD];
        float Bv = xdp[t * 80 + RR + n];
        float Cv = xdp[t * 80 + RR + NNs + n];
        float dA = __expf(dtv * Acoef);
        h = dA * h + dtv * Bv * xcv;
        float part = h * Cv;
        part += __shfl_xor(part, 8, 16);
        part += __shfl_xor(part, 4, 16);
        part += __shfl_xor(part, 2, 16);
        part += __shfl_xor(part, 1, 16);
        if (n == 0) {
            float zv = zp[(size_t)t * DD];
            zp[(size_t)t * DD] = (part + Dv * xcv) * silu_f(zv);
        }
    }
}

// ---------------------------------------------------------------------------
extern "C" void kernel_launch(void* const* d_in, const int* in_sizes, int n_in,
                              void* d_out, int out_size, void* d_ws, size_t ws_size,
                              hipStream_t stream) {
    const float* x      = (const float*)d_in[0];
    // d_in[1] batch_params, d_in[2] has_velocity: provably no effect (see analysis)
    const float* norm_w = (const float*)d_in[3];
    const float* in_w   = (const float*)d_in[4];
    const float* in_b   = (const float*)d_in[5];
    const float* conv_w = (const float*)d_in[6];
    const float* conv_b = (const float*)d_in[7];
    const float* xp_w   = (const float*)d_in[8];
    const float* dt_w   = (const float*)d_in[9];
    const float* dt_b   = (const float*)d_in[10];
    const float* A_log  = (const float*)d_in[11];
    const float* Dp     = (const float*)d_in[12];
    const float* out_w  = (const float*)d_in[13];
    const float* out_b  = (const float*)d_in[14];
    float* out = (float*)d_out;

    const size_t S = (size_t)BB * LL * DD;     // 6291456
    float* res  = (float*)d_ws;                // residual
    float* hid  = res + S;                     // hidden, later x_conv
    float* xin  = hid + S;                     // x_in, later dt
    float* z    = xin + S;                     // z, later y (in-place)
    float* xdbl = z + S;                       // (B*L, 80)

    const int M = BB * LL;                     // 8192

    // 1. pos + residual + rmsnorm
    k_pos_rms<<<M, 256, 0, stream>>>(x, norm_w, res, hid);

    // 2. in_proj: xz = hid @ in_w^T + in_b  -> split into xin | z
    gemm_nt<1><<<dim3(1536 / 64, M / 64), 256, 0, stream>>>(
        hid, DD, in_w, DD, M, 2 * DD, DD, in_b, nullptr, xin, z, 0);

    // 3. depthwise conv + silu  (xin -> hid)
    k_conv<<<(int)(S / 256), 256, 0, stream>>>(xin, conv_w, conv_b, hid);

    // 4. x_proj: xdbl = x_conv @ xp_w^T   (no bias)
    gemm_nt<0><<<dim3(2, M / 64), 256, 0, stream>>>(
        hid, DD, xp_w, DD, M, RR + 2 * NNs, DD, nullptr, nullptr, xdbl, nullptr, 80);

    // 5. dt_proj + softplus: dt = softplus(xdbl[:, :48] @ dt_w^T + dt_b) -> xin
    gemm_nt<2><<<dim3(DD / 64, M / 64), 256, 0, stream>>>(
        xdbl, 80, dt_w, RR, M, DD, RR, dt_b, nullptr, xin, nullptr, DD);

    // 6. selective scan + gating (z buffer becomes y in-place)
    k_scan<<<(BB * DD * NNs) / 256, 256, 0, stream>>>(xin, hid, xdbl, A_log, Dp, z);

    // 7. out_proj + bias + residual -> d_out
    gemm_nt<3><<<dim3(DD / 64, M / 64), 256, 0, stream>>>(
        z, DD, out_w, DD, M, DD, DD, out_b, res, out, nullptr, DD);
}

// Round 2
// 940.584 us; speedup vs baseline: 1.3843x; 1.3843x over previous
//
#include <hip/hip_runtime.h>
#include <math.h>

#define BB 8
#define LL 1024
#define DD 768
#define NNs 16
#define RR 48

__device__ __forceinline__ float silu_f(float v) { return v / (1.0f + __expf(-v)); }

// ---------------------------------------------------------------------------
// K1: pos embedding (analytic) + residual + RMSNorm. One block per (b,l) row.
// ---------------------------------------------------------------------------
__global__ __launch_bounds__(256) void k_pos_rms(const float* __restrict__ x,
                                                 const float* __restrict__ norm_w,
                                                 float* __restrict__ res,
                                                 float* __restrict__ hid) {
    int row = blockIdx.x;            // b*L + l
    int l = row & (LL - 1);
    int d3 = l & 3;
    int w = (l >> 2) & 15;
    int h = l >> 6;
    float coord[3] = { h * (1.0f / 15.0f), w * (1.0f / 15.0f), d3 * (1.0f / 3.0f) };
    const float LOG1E4 = 9.210340371976184f;   // ln(10000)
    int t = threadIdx.x;
    float r[3];
    float s = 0.0f;
#pragma unroll
    for (int i = 0; i < 3; i++) {
        int j = t + i * 256;
        int c = j >> 8;              // channel 0..2
        int fp = j & 255;
        int f = fp & 127;
        float omega = __expf(-(f * (1.0f / 128.0f)) * LOG1E4);
        float arg = coord[c] * omega;
        float pv = (fp < 128) ? __sinf(arg) : __cosf(arg);
        float rv = x[(size_t)row * DD + j] + pv;
        r[i] = rv;
        s += rv * rv;
    }
    // reduce over 256 threads: wave64 shuffle + LDS
#pragma unroll
    for (int off = 32; off; off >>= 1) s += __shfl_xor(s, off, 64);
    __shared__ float ls[4];
    if ((t & 63) == 0) ls[t >> 6] = s;
    __syncthreads();
    s = ls[0] + ls[1] + ls[2] + ls[3];
    float rs = rsqrtf(s * (1.0f / DD) + 1e-5f);
#pragma unroll
    for (int i = 0; i < 3; i++) {
        int j = t + i * 256;
        res[(size_t)row * DD + j] = r[i];
        hid[(size_t)row * DD + j] = r[i] * rs * norm_w[j];
    }
}

// ---------------------------------------------------------------------------
// Generic NT GEMM: C[m][n] = sum_k A[m][k] * Bw[n][k] (+bias) with epilogues.
// BM=BN=64, BK=16, 256 threads, 4x4 per thread. M assumed multiple of 64.
// MODE 0: plain store (bias optional)      MODE 1: split write (xz -> xin|z)
// MODE 2: softplus                         MODE 3: + residual
// ---------------------------------------------------------------------------
template <int MODE>
__global__ __launch_bounds__(256) void gemm_nt(const float* __restrict__ A, int lda,
                                               const float* __restrict__ Bw, int ldb,
                                               int M, int N, int Kd,
                                               const float* __restrict__ bias,
                                               const float* __restrict__ resid,
                                               float* __restrict__ C0,
                                               float* __restrict__ C1, int ldc) {
    __shared__ __align__(16) float As[16][68];
    __shared__ __align__(16) float Bs[16][68];
    int m0 = blockIdx.y * 64;
    int n0 = blockIdx.x * 64;
    int t = threadIdx.x;
    int tx = t & 15, ty = t >> 4;
    int ar = t >> 2;           // 0..63 tile row
    int ak = (t & 3) * 4;      // 0,4,8,12
    float acc[4][4] = {};
    for (int k0 = 0; k0 < Kd; k0 += 16) {
        float4 av = *(const float4*)(A + (size_t)(m0 + ar) * lda + k0 + ak);
        int brow = n0 + ar;
        if (brow >= N) brow = N - 1;
        float4 bv = *(const float4*)(Bw + (size_t)brow * ldb + k0 + ak);
        As[ak + 0][ar] = av.x; As[ak + 1][ar] = av.y;
        As[ak + 2][ar] = av.z; As[ak + 3][ar] = av.w;
        Bs[ak + 0][ar] = bv.x; Bs[ak + 1][ar] = bv.y;
        Bs[ak + 2][ar] = bv.z; Bs[ak + 3][ar] = bv.w;
        __syncthreads();
#pragma unroll
        for (int kk = 0; kk < 16; kk++) {
            float4 a4 = *(const float4*)&As[kk][ty * 4];
            float4 b4 = *(const float4*)&Bs[kk][tx * 4];
            float aa[4] = { a4.x, a4.y, a4.z, a4.w };
            float bb[4] = { b4.x, b4.y, b4.z, b4.w };
#pragma unroll
            for (int i = 0; i < 4; i++)
#pragma unroll
                for (int j = 0; j < 4; j++) acc[i][j] += aa[i] * bb[j];
        }
        __syncthreads();
    }
#pragma unroll
    for (int i = 0; i < 4; i++) {
        int m = m0 + ty * 4 + i;
#pragma unroll
        for (int j = 0; j < 4; j++) {
            int n = n0 + tx * 4 + j;
            if (n >= N) continue;
            float v = acc[i][j] + (bias ? bias[n] : 0.0f);
            if (MODE == 0) {
                C0[(size_t)m * ldc + n] = v;
            } else if (MODE == 1) {
                if (n < DD) C0[(size_t)m * DD + n] = v;
                else        C1[(size_t)m * DD + (n - DD)] = v;
            } else if (MODE == 2) {
                C0[(size_t)m * ldc + n] = (v > 20.0f) ? v : log1pf(__expf(v));
            } else {  // MODE 3
                C0[(size_t)m * ldc + n] = v + resid[(size_t)m * DD + n];
            }
        }
    }
}

// ---------------------------------------------------------------------------
// K3: depthwise causal conv (K=4) + bias + silu
// ---------------------------------------------------------------------------
__global__ __launch_bounds__(256) void k_conv(const float* __restrict__ xin,
                                              const float* __restrict__ cw,
                                              const float* __restrict__ cb,
                                              float* __restrict__ xc) {
    size_t gid = (size_t)blockIdx.x * 256 + threadIdx.x;
    int d = (int)(gid % DD);
    int bt = (int)(gid / DD);        // b*L + t
    int tt = bt & (LL - 1);
    float4 w = ((const float4*)cw)[d];   // conv_w[d,0,0..3]
    const float* p = xin + (size_t)bt * DD + d;
    float acc = cb[d];
    if (tt >= 3) acc += p[-3 * DD] * w.x;
    if (tt >= 2) acc += p[-2 * DD] * w.y;
    if (tt >= 1) acc += p[-1 * DD] * w.z;
    acc += p[0] * w.w;
    xc[gid] = silu_f(acc);
}

// ---------------------------------------------------------------------------
// K5: chunked selective scan. One block per (b,d); threads = chunk*16 + n
// (16 chunks of 64 timesteps x 16 state dims).
// Phase 1: each thread scans its chunk from h=0 -> (P = prod dA, S = local h).
// Phase 2: 16 threads serially combine chunk summaries in LDS -> h_in per chunk.
// Phase 3: rescan chunk from h_in, shfl-16 reduce y over n, gate with silu(z).
// Writes y in-place into the z buffer.
// ---------------------------------------------------------------------------
__global__ __launch_bounds__(256) void k_scan(const float* __restrict__ dt,
                                              const float* __restrict__ xc,
                                              const float* __restrict__ xdbl,
                                              const float* __restrict__ A_log,
                                              const float* __restrict__ Dp,
                                              float* __restrict__ zy) {
    int blk = blockIdx.x;            // b*768 + d
    int b = blk / DD;
    int d = blk % DD;
    int tid = threadIdx.x;
    int n = tid & 15;
    int c = tid >> 4;                // chunk 0..15
    const int CL = LL / 16;          // 64 timesteps per chunk

    float Acoef = -__expf(A_log[d * NNs + n]);
    const float* dtp = dt + (size_t)b * LL * DD + d;
    const float* xcp = xc + (size_t)b * LL * DD + d;
    const float* xdp = xdbl + (size_t)b * LL * 80;
    float* zp = zy + (size_t)b * LL * DD + d;
    int t0 = c * CL;

    // Phase 1: local scan from zero state
    float P = 1.0f, S = 0.0f;
    for (int i = 0; i < CL; i++) {
        int t = t0 + i;
        float dtv = dtp[(size_t)t * DD];
        float xcv = xcp[(size_t)t * DD];
        float Bv = xdp[t * 80 + RR + n];
        float dA = __expf(dtv * Acoef);
        S = dA * S + dtv * Bv * xcv;
        P *= dA;
    }

    __shared__ float Pl[16][16];
    __shared__ float Sl[16][16];
    __shared__ float Hl[16][16];
    Pl[c][n] = P;
    Sl[c][n] = S;
    __syncthreads();

    // Phase 2: serial combine across chunks (one thread per n)
    if (tid < 16) {
        float h = 0.0f;
#pragma unroll
        for (int cc = 0; cc < 16; cc++) {
            Hl[cc][tid] = h;
            h = Pl[cc][tid] * h + Sl[cc][tid];
        }
    }
    __syncthreads();

    // Phase 3: rescan from h_in, produce gated output
    float h = Hl[c][n];
    float Dv = Dp[d];
    for (int i = 0; i < CL; i++) {
        int t = t0 + i;
        float dtv = dtp[(size_t)t * DD];
        float xcv = xcp[(size_t)t * DD];
        float Bv = xdp[t * 80 + RR + n];
        float Cv = xdp[t * 80 + RR + NNs + n];
        float dA = __expf(dtv * Acoef);
        h = dA * h + dtv * Bv * xcv;
        float part = h * Cv;
        part += __shfl_xor(part, 8, 16);
        part += __shfl_xor(part, 4, 16);
        part += __shfl_xor(part, 2, 16);
        part += __shfl_xor(part, 1, 16);
        if (n == 0) {
            float zv = zp[(size_t)t * DD];
            zp[(size_t)t * DD] = (part + Dv * xcv) * silu_f(zv);
        }
    }
}

// ---------------------------------------------------------------------------
extern "C" void kernel_launch(void* const* d_in, const int* in_sizes, int n_in,
                              void* d_out, int out_size, void* d_ws, size_t ws_size,
                              hipStream_t stream) {
    const float* x      = (const float*)d_in[0];
    // d_in[1] batch_params, d_in[2] has_velocity: provably no effect (pos embed
    // normalization cancels them; see analysis)
    const float* norm_w = (const float*)d_in[3];
    const float* in_w   = (const float*)d_in[4];
    const float* in_b   = (const float*)d_in[5];
    const float* conv_w = (const float*)d_in[6];
    const float* conv_b = (const float*)d_in[7];
    const float* xp_w   = (const float*)d_in[8];
    const float* dt_w   = (const float*)d_in[9];
    const float* dt_b   = (const float*)d_in[10];
    const float* A_log  = (const float*)d_in[11];
    const float* Dp     = (const float*)d_in[12];
    const float* out_w  = (const float*)d_in[13];
    const float* out_b  = (const float*)d_in[14];
    float* out = (float*)d_out;

    const size_t S = (size_t)BB * LL * DD;     // 6291456
    float* res  = (float*)d_ws;                // residual
    float* hid  = res + S;                     // hidden, later x_conv
    float* xin  = hid + S;                     // x_in, later dt
    float* z    = xin + S;                     // z, later y (in-place)
    float* xdbl = z + S;                       // (B*L, 80)

    const int M = BB * LL;                     // 8192

    // 1. pos + residual + rmsnorm
    k_pos_rms<<<M, 256, 0, stream>>>(x, norm_w, res, hid);

    // 2. in_proj: xz = hid @ in_w^T + in_b  -> split into xin | z
    gemm_nt<1><<<dim3(1536 / 64, M / 64), 256, 0, stream>>>(
        hid, DD, in_w, DD, M, 2 * DD, DD, in_b, nullptr, xin, z, 0);

    // 3. depthwise conv + silu  (xin -> hid)
    k_conv<<<(int)(S / 256), 256, 0, stream>>>(xin, conv_w, conv_b, hid);

    // 4. x_proj: xdbl = x_conv @ xp_w^T   (no bias)
    gemm_nt<0><<<dim3(2, M / 64), 256, 0, stream>>>(
        hid, DD, xp_w, DD, M, RR + 2 * NNs, DD, nullptr, nullptr, xdbl, nullptr, 80);

    // 5. dt_proj + softplus: dt = softplus(xdbl[:, :48] @ dt_w^T + dt_b) -> xin
    gemm_nt<2><<<dim3(DD / 64, M / 64), 256, 0, stream>>>(
        xdbl, 80, dt_w, RR, M, DD, RR, dt_b, nullptr, xin, nullptr, DD);

    // 6. chunked selective scan + gating (z buffer becomes y in-place)
    k_scan<<<BB * DD, 256, 0, stream>>>(xin, hid, xdbl, A_log, Dp, z);

    // 7. out_proj + bias + residual -> d_out
    gemm_nt<3><<<dim3(DD / 64, M / 64), 256, 0, stream>>>(
        z, DD, out_w, DD, M, DD, DD, out_b, res, out, nullptr, DD);
}

// Round 3
// 775.403 us; speedup vs baseline: 1.6792x; 1.2130x over previous
//
#include <hip/hip_runtime.h>
#include <math.h>

#define BB 8
#define LL 1024
#define DD 768
#define NNs 16
#define RR 48

__device__ __forceinline__ float silu_f(float v) { return v / (1.0f + __expf(-v)); }

// ---------------------------------------------------------------------------
// K1: pos embedding (analytic) + residual + RMSNorm. One block per (b,l) row.
// pos is provably independent of batch_params/has_velocity: the per-channel
// min/max normalization cancels the (positive) resolutions exactly, leaving
// coords = (h/15, w/15, d/3).
// ---------------------------------------------------------------------------
__global__ __launch_bounds__(256) void k_pos_rms(const float* __restrict__ x,
                                                 const float* __restrict__ norm_w,
                                                 float* __restrict__ res,
                                                 float* __restrict__ hid) {
    int row = blockIdx.x;            // b*L + l
    int l = row & (LL - 1);
    int d3 = l & 3;
    int w = (l >> 2) & 15;
    int h = l >> 6;
    float coord[3] = { h * (1.0f / 15.0f), w * (1.0f / 15.0f), d3 * (1.0f / 3.0f) };
    const float LOG1E4 = 9.210340371976184f;   // ln(10000)
    int t = threadIdx.x;
    float r[3];
    float s = 0.0f;
#pragma unroll
    for (int i = 0; i < 3; i++) {
        int j = t + i * 256;
        int c = j >> 8;              // channel 0..2
        int fp = j & 255;
        int f = fp & 127;
        float omega = __expf(-(f * (1.0f / 128.0f)) * LOG1E4);
        float arg = coord[c] * omega;
        float pv = (fp < 128) ? __sinf(arg) : __cosf(arg);
        float rv = x[(size_t)row * DD + j] + pv;
        r[i] = rv;
        s += rv * rv;
    }
#pragma unroll
    for (int off = 32; off; off >>= 1) s += __shfl_xor(s, off, 64);
    __shared__ float ls[4];
    if ((t & 63) == 0) ls[t >> 6] = s;
    __syncthreads();
    s = ls[0] + ls[1] + ls[2] + ls[3];
    float rs = rsqrtf(s * (1.0f / DD) + 1e-5f);
#pragma unroll
    for (int i = 0; i < 3; i++) {
        int j = t + i * 256;
        res[(size_t)row * DD + j] = r[i];
        hid[(size_t)row * DD + j] = r[i] * rs * norm_w[j];
    }
}

// ---------------------------------------------------------------------------
// NT GEMM: C[m][n] = sum_k A[m][k]*Bw[n][k] + bias. BM=BN=64, BK=16, 256 thr.
// MODE 1 (in_proj): n<768 -> xin[m][n] (float4); n>=768 -> zT[b][n-768][t]
//                   transposed float4-over-t store.
// MODE 2 (dt_proj): softplus, transposed store -> dtT[b][n][t].
// ---------------------------------------------------------------------------
template <int MODE>
__global__ __launch_bounds__(256) void gemm_nt(const float* __restrict__ A, int lda,
                                               const float* __restrict__ Bw, int ldb,
                                               int N, int Kd,
                                               const float* __restrict__ bias,
                                               float* __restrict__ C0,
                                               float* __restrict__ C1) {
    __shared__ __align__(16) float As[16][68];
    __shared__ __align__(16) float Bs[16][68];
    int m0 = blockIdx.y * 64;
    int n0 = blockIdx.x * 64;
    int t = threadIdx.x;
    int tx = t & 15, ty = t >> 4;
    int ar = t >> 2;
    int ak = (t & 3) * 4;
    float acc[4][4] = {};
    for (int k0 = 0; k0 < Kd; k0 += 16) {
        float4 av = *(const float4*)(A + (size_t)(m0 + ar) * lda + k0 + ak);
        int brow = n0 + ar;
        if (brow >= N) brow = N - 1;
        float4 bv = *(const float4*)(Bw + (size_t)brow * ldb + k0 + ak);
        As[ak + 0][ar] = av.x; As[ak + 1][ar] = av.y;
        As[ak + 2][ar] = av.z; As[ak + 3][ar] = av.w;
        Bs[ak + 0][ar] = bv.x; Bs[ak + 1][ar] = bv.y;
        Bs[ak + 2][ar] = bv.z; Bs[ak + 3][ar] = bv.w;
        __syncthreads();
#pragma unroll
        for (int kk = 0; kk < 16; kk++) {
            float4 a4 = *(const float4*)&As[kk][ty * 4];
            float4 b4 = *(const float4*)&Bs[kk][tx * 4];
            float aa[4] = { a4.x, a4.y, a4.z, a4.w };
            float bb[4] = { b4.x, b4.y, b4.z, b4.w };
#pragma unroll
            for (int i = 0; i < 4; i++)
#pragma unroll
                for (int j = 0; j < 4; j++) acc[i][j] += aa[i] * bb[j];
        }
        __syncthreads();
    }
    int b = m0 >> 10;
    int t0m = m0 & (LL - 1);
    if (MODE == 1 && n0 < DD) {
        // x-part: normal (b,t,d) layout, float4 over n
        float4 bi = *(const float4*)(bias + n0 + tx * 4);
#pragma unroll
        for (int i = 0; i < 4; i++) {
            int m = m0 + ty * 4 + i;
            float4 v = { acc[i][0] + bi.x, acc[i][1] + bi.y,
                         acc[i][2] + bi.z, acc[i][3] + bi.w };
            *(float4*)(C0 + (size_t)m * DD + n0 + tx * 4) = v;
        }
    } else {
        // transposed (b,d,t) layout, float4 over t
#pragma unroll
        for (int j = 0; j < 4; j++) {
            int n = n0 + tx * 4 + j;
            float bb = bias[n];
            float v0 = acc[0][j] + bb, v1 = acc[1][j] + bb;
            float v2 = acc[2][j] + bb, v3 = acc[3][j] + bb;
            if (MODE == 2) {
                v0 = (v0 > 20.0f) ? v0 : log1pf(__expf(v0));
                v1 = (v1 > 20.0f) ? v1 : log1pf(__expf(v1));
                v2 = (v2 > 20.0f) ? v2 : log1pf(__expf(v2));
                v3 = (v3 > 20.0f) ? v3 : log1pf(__expf(v3));
            }
            float* dst;
            if (MODE == 1) dst = C1 + ((size_t)(b * DD + (n - DD))) * LL + t0m + ty * 4;
            else           dst = C0 + ((size_t)(b * DD + n)) * LL + t0m + ty * 4;
            float4 v = { v0, v1, v2, v3 };
            *(float4*)dst = v;
        }
    }
}

// ---------------------------------------------------------------------------
// TN GEMM: A is K-major (b,k,t) layout (At row = b*Kd + k, length L).
// C[m][n] = sum_k At[b][k][t]*Bw[n][k].  M from grid (tiles never cross b).
// MODE 0 (x_proj): plain store, ldc, guard n<N.  MODE 3 (out_proj): +bias+resid.
// ---------------------------------------------------------------------------
template <int MODE>
__global__ __launch_bounds__(256) void gemm_tn(const float* __restrict__ At,
                                               const float* __restrict__ Bw, int ldb,
                                               int N, int Kd,
                                               const float* __restrict__ bias,
                                               const float* __restrict__ resid,
                                               float* __restrict__ C0, int ldc) {
    __shared__ __align__(16) float As[16][68];
    __shared__ __align__(16) float Bs[16][68];
    int m0 = blockIdx.y * 64;
    int n0 = blockIdx.x * 64;
    int b = m0 >> 10;
    int t0m = m0 & (LL - 1);
    int t = threadIdx.x;
    int tx = t & 15, ty = t >> 4;
    int kk = t >> 4, tt = t & 15;      // A staging: row k, float4 over t
    int ar = t >> 2, ak = (t & 3) * 4; // B staging (same as NT)
    float acc[4][4] = {};
    for (int k0 = 0; k0 < Kd; k0 += 16) {
        float4 av = *(const float4*)(At + ((size_t)(b * Kd + k0 + kk)) * LL + t0m + tt * 4);
        int brow = n0 + ar;
        if (brow >= N) brow = N - 1;
        float4 bv = *(const float4*)(Bw + (size_t)brow * ldb + k0 + ak);
        *(float4*)&As[kk][tt * 4] = av;
        Bs[ak + 0][ar] = bv.x; Bs[ak + 1][ar] = bv.y;
        Bs[ak + 2][ar] = bv.z; Bs[ak + 3][ar] = bv.w;
        __syncthreads();
#pragma unroll
        for (int kq = 0; kq < 16; kq++) {
            float4 a4 = *(const float4*)&As[kq][ty * 4];
            float4 b4 = *(const float4*)&Bs[kq][tx * 4];
            float aa[4] = { a4.x, a4.y, a4.z, a4.w };
            float bb[4] = { b4.x, b4.y, b4.z, b4.w };
#pragma unroll
            for (int i = 0; i < 4; i++)
#pragma unroll
                for (int j = 0; j < 4; j++) acc[i][j] += aa[i] * bb[j];
        }
        __syncthreads();
    }
    if (MODE == 0) {
        int n = n0 + tx * 4;
        if (n + 3 < N) {
#pragma unroll
            for (int i = 0; i < 4; i++) {
                int m = m0 + ty * 4 + i;
                float4 v = { acc[i][0], acc[i][1], acc[i][2], acc[i][3] };
                *(float4*)(C0 + (size_t)m * ldc + n) = v;
            }
        }
    } else {
        float4 bi = *(const float4*)(bias + n0 + tx * 4);
#pragma unroll
        for (int i = 0; i < 4; i++) {
            int m = m0 + ty * 4 + i;
            float4 rv = *(const float4*)(resid + (size_t)m * DD + n0 + tx * 4);
            float4 v = { acc[i][0] + bi.x + rv.x, acc[i][1] + bi.y + rv.y,
                         acc[i][2] + bi.z + rv.z, acc[i][3] + bi.w + rv.w };
            *(float4*)(C0 + (size_t)m * DD + n0 + tx * 4) = v;
        }
    }
}

// ---------------------------------------------------------------------------
// K3: transposing depthwise causal conv (K=4) + bias + silu.
// Block = (b, 64t x 64d tile). Coalesced load (t,d) -> LDS, conv, LDS
// transpose, coalesced store to xcT in (b,d,t) layout.
// ---------------------------------------------------------------------------
__global__ __launch_bounds__(256) void k_conv_t(const float* __restrict__ xin,
                                                const float* __restrict__ cw,
                                                const float* __restrict__ cb,
                                                float* __restrict__ xcT) {
    __shared__ float Xs[67][68];
    __shared__ float Ys[64][65];
    int b = blockIdx.y;
    int dtile = blockIdx.x % 12;
    int ttile = blockIdx.x / 12;
    int t0 = ttile * 64, d0 = dtile * 64;
    int tid = threadIdx.x;
#pragma unroll
    for (int p = 0; p < 5; p++) {
        int row = p * 16 + (tid >> 4);
        if (row < 67) {
            int col = (tid & 15) * 4;
            int tg = t0 - 3 + row;
            float4 v = { 0.f, 0.f, 0.f, 0.f };
            if (tg >= 0) v = *(const float4*)(xin + ((size_t)(b * LL + tg)) * DD + d0 + col);
            *(float4*)&Xs[row][col] = v;
        }
    }
    __syncthreads();
    int dl = tid & 63, wid = tid >> 6;
    float4 w = ((const float4*)cw)[d0 + dl];
    float bv = cb[d0 + dl];
#pragma unroll
    for (int e = 0; e < 16; e++) {
        int tl = e * 4 + wid;
        float acc = bv + Xs[tl + 0][dl] * w.x + Xs[tl + 1][dl] * w.y
                       + Xs[tl + 2][dl] * w.z + Xs[tl + 3][dl] * w.w;
        Ys[dl][tl] = silu_f(acc);
    }
    __syncthreads();
    int tl2 = tid & 63, wd = tid >> 6;
#pragma unroll
    for (int e = 0; e < 16; e++) {
        int dl2 = e * 4 + wd;
        xcT[((size_t)(b * DD + d0 + dl2)) * LL + t0 + tl2] = Ys[dl2][tl2];
    }
}

// ---------------------------------------------------------------------------
// K5: chunked selective scan, all operands (b,d,t) contiguous per block.
// Block per (b,d); threads = 16 chunks x 16 n. Gates in-place into zT.
// ---------------------------------------------------------------------------
__global__ __launch_bounds__(256) void k_scan(const float* __restrict__ dtT,
                                              const float* __restrict__ xcT,
                                              const float* __restrict__ xdbl,
                                              const float* __restrict__ A_log,
                                              const float* __restrict__ Dp,
                                              float* __restrict__ zy) {
    int blk = blockIdx.x;            // b*768 + d
    int b = blk / DD;
    int d = blk - b * DD;
    int tid = threadIdx.x;
    int n = tid & 15;
    int c = tid >> 4;
    size_t base = (size_t)blk * LL;
    const float* dtp = dtT + base;
    const float* xcp = xcT + base;
    float* zp = zy + base;
    const float* xdp = xdbl + (size_t)b * LL * 80;
    float Acoef = -__expf(A_log[d * NNs + n]);
    int t0 = c * 64;

    // Phase 1: local scan from zero state
    float P = 1.0f, S = 0.0f;
    for (int i = 0; i < 64; i += 4) {
        float4 d4 = *(const float4*)(dtp + t0 + i);
        float4 x4 = *(const float4*)(xcp + t0 + i);
        float dv[4] = { d4.x, d4.y, d4.z, d4.w };
        float xv[4] = { x4.x, x4.y, x4.z, x4.w };
#pragma unroll
        for (int j = 0; j < 4; j++) {
            int tg = t0 + i + j;
            float Bv = xdp[tg * 80 + RR + n];
            float dA = __expf(dv[j] * Acoef);
            S = dA * S + dv[j] * Bv * xv[j];
            P *= dA;
        }
    }

    __shared__ float Pl[16][17];
    __shared__ float Sl[16][17];
    __shared__ float Hl[16][17];
    Pl[c][n] = P;
    Sl[c][n] = S;
    __syncthreads();
    if (tid < 16) {
        float h = 0.0f;
#pragma unroll
        for (int cc = 0; cc < 16; cc++) {
            Hl[cc][tid] = h;
            h = Pl[cc][tid] * h + Sl[cc][tid];
        }
    }
    __syncthreads();

    // Phase 3: rescan from h_in, gate, write in place (float4 over t)
    float h = Hl[c][n];
    float Dv = Dp[d];
    for (int i = 0; i < 64; i += 4) {
        float4 d4 = *(const float4*)(dtp + t0 + i);
        float4 x4 = *(const float4*)(xcp + t0 + i);
        float dv[4] = { d4.x, d4.y, d4.z, d4.w };
        float xv[4] = { x4.x, x4.y, x4.z, x4.w };
        float4 z4;
        if (n == 0) z4 = *(const float4*)(zp + t0 + i);
        float yv[4];
#pragma unroll
        for (int j = 0; j < 4; j++) {
            int tg = t0 + i + j;
            float Bv = xdp[tg * 80 + RR + n];
            float Cv = xdp[tg * 80 + RR + NNs + n];
            float dA = __expf(dv[j] * Acoef);
            h = dA * h + dv[j] * Bv * xv[j];
            float part = h * Cv;
            part += __shfl_xor(part, 8, 16);
            part += __shfl_xor(part, 4, 16);
            part += __shfl_xor(part, 2, 16);
            part += __shfl_xor(part, 1, 16);
            yv[j] = part + Dv * xv[j];
        }
        if (n == 0) {
            float4 o = { yv[0] * silu_f(z4.x), yv[1] * silu_f(z4.y),
                         yv[2] * silu_f(z4.z), yv[3] * silu_f(z4.w) };
            *(float4*)(zp + t0 + i) = o;
        }
    }
}

// ---------------------------------------------------------------------------
extern "C" void kernel_launch(void* const* d_in, const int* in_sizes, int n_in,
                              void* d_out, int out_size, void* d_ws, size_t ws_size,
                              hipStream_t stream) {
    const float* x      = (const float*)d_in[0];
    // d_in[1] batch_params, d_in[2] has_velocity: provably no effect
    const float* norm_w = (const float*)d_in[3];
    const float* in_w   = (const float*)d_in[4];
    const float* in_b   = (const float*)d_in[5];
    const float* conv_w = (const float*)d_in[6];
    const float* conv_b = (const float*)d_in[7];
    const float* xp_w   = (const float*)d_in[8];
    const float* dt_w   = (const float*)d_in[9];
    const float* dt_b   = (const float*)d_in[10];
    const float* A_log  = (const float*)d_in[11];
    const float* Dp     = (const float*)d_in[12];
    const float* out_w  = (const float*)d_in[13];
    const float* out_b  = (const float*)d_in[14];
    float* out = (float*)d_out;

    const size_t S = (size_t)BB * LL * DD;     // 6291456
    float* res  = (float*)d_ws;                // residual
    float* hid  = res + S;                     // rmsnorm out, then xcT
    float* xin  = hid + S;                     // x_in, then dtT
    float* zT   = xin + S;                     // z (b,d,t), gated y in place
    float* xdbl = zT + S;                      // (B*L, 80)

    const int M = BB * LL;                     // 8192

    // 1. pos + residual + rmsnorm
    k_pos_rms<<<M, 256, 0, stream>>>(x, norm_w, res, hid);

    // 2. in_proj: xz = hid @ in_w^T + in_b -> xin (b,t,d) | zT (b,d,t)
    gemm_nt<1><<<dim3(1536 / 64, M / 64), 256, 0, stream>>>(
        hid, DD, in_w, DD, 2 * DD, DD, in_b, xin, zT);

    // 3. transposing depthwise conv + silu: xin -> xcT (reuses hid buffer)
    k_conv_t<<<dim3(192, BB), 256, 0, stream>>>(xin, conv_w, conv_b, hid);

    // 4. x_proj (TN): xdbl = xcT^T @ xp_w^T
    gemm_tn<0><<<dim3(2, M / 64), 256, 0, stream>>>(
        hid, xp_w, DD, RR + 2 * NNs, DD, nullptr, nullptr, xdbl, 80);

    // 5. dt_proj + softplus -> dtT (reuses xin buffer)
    gemm_nt<2><<<dim3(DD / 64, M / 64), 256, 0, stream>>>(
        xdbl, 80, dt_w, RR, DD, RR, dt_b, xin, nullptr);

    // 6. chunked selective scan + gating (zT becomes gated y in place)
    k_scan<<<BB * DD, 256, 0, stream>>>(xin, hid, xdbl, A_log, Dp, zT);

    // 7. out_proj (TN) + bias + residual -> d_out
    gemm_tn<3><<<dim3(DD / 64, M / 64), 256, 0, stream>>>(
        zT, out_w, DD, DD, DD, out_b, res, out, DD);
}

// Round 4
// 423.232 us; speedup vs baseline: 3.0764x; 1.8321x over previous
//
#include <hip/hip_runtime.h>
#include <math.h>

#define BB 8
#define LL 1024
#define DD 768
#define NNs 16
#define RR 48

typedef __attribute__((ext_vector_type(8))) short bf16x8;
typedef __attribute__((ext_vector_type(4))) float f32x4;

__device__ __forceinline__ float silu_f(float v) { return v / (1.0f + __expf(-v)); }

__device__ __forceinline__ short f2bf(float f) {
    union { float f; unsigned u; } v; v.f = f;
    unsigned r = (v.u + 0x7fffu + ((v.u >> 16) & 1u)) >> 16;
    return (short)r;
}

__device__ __forceinline__ void async16(const void* g, void* l) {
    __builtin_amdgcn_global_load_lds((const __attribute__((address_space(1))) void*)g,
                                     (__attribute__((address_space(3))) void*)l,
                                     16, 0, 0);
}

// ---------------------------------------------------------------------------
// K0: fp32 -> bf16 weight conversion (grid-stride over float4)
// ---------------------------------------------------------------------------
__global__ __launch_bounds__(256) void k_cvt(const float* __restrict__ src,
                                             short* __restrict__ dst, int n4) {
    int i = blockIdx.x * 256 + threadIdx.x;
    if (i < n4) {
        float4 v = ((const float4*)src)[i];
        short4 o = { f2bf(v.x), f2bf(v.y), f2bf(v.z), f2bf(v.w) };
        ((short4*)dst)[i] = o;
    }
}

// ---------------------------------------------------------------------------
// K1: pos embedding (analytic; batch_params/has_velocity provably cancel) +
// residual + RMSNorm. res fp32, hidden out in bf16 (MFMA A operand).
// ---------------------------------------------------------------------------
__global__ __launch_bounds__(256) void k_pos_rms(const float* __restrict__ x,
                                                 const float* __restrict__ norm_w,
                                                 float* __restrict__ res,
                                                 short* __restrict__ hidb) {
    int row = blockIdx.x;            // b*L + l
    int l = row & (LL - 1);
    int d3 = l & 3;
    int w = (l >> 2) & 15;
    int h = l >> 6;
    float coord[3] = { h * (1.0f / 15.0f), w * (1.0f / 15.0f), d3 * (1.0f / 3.0f) };
    const float LOG1E4 = 9.210340371976184f;   // ln(10000)
    int t = threadIdx.x;
    float r[3];
    float s = 0.0f;
#pragma unroll
    for (int i = 0; i < 3; i++) {
        int j = t + i * 256;
        int c = j >> 8;
        int fp = j & 255;
        int f = fp & 127;
        float omega = __expf(-(f * (1.0f / 128.0f)) * LOG1E4);
        float arg = coord[c] * omega;
        float pv = (fp < 128) ? __sinf(arg) : __cosf(arg);
        float rv = x[(size_t)row * DD + j] + pv;
        r[i] = rv;
        s += rv * rv;
    }
#pragma unroll
    for (int off = 32; off; off >>= 1) s += __shfl_xor(s, off, 64);
    __shared__ float ls[4];
    if ((t & 63) == 0) ls[t >> 6] = s;
    __syncthreads();
    s = ls[0] + ls[1] + ls[2] + ls[3];
    float rs = rsqrtf(s * (1.0f / DD) + 1e-5f);
#pragma unroll
    for (int i = 0; i < 3; i++) {
        int j = t + i * 256;
        res[(size_t)row * DD + j] = r[i];
        hidb[(size_t)row * DD + j] = f2bf(r[i] * rs * norm_w[j]);
    }
}

// ---------------------------------------------------------------------------
// MFMA bf16 GEMM (NT): C[m][n] = sum_k A[m][k]*Bw[n][k], A MxK, Bw NxK bf16.
// 128x128 tile, BK=32, 256 thr (4 waves, 2x2 wave grid, 4x4 16x16 accs each).
// global_load_lds(16B) into fragment-ordered LDS; conflict-free ds_read_b128.
// EPI 1 (in_proj): +bias; n<768 -> C0=xin (b,t,d); n>=768 -> C1=zT (b,d,t).
// EPI 3 (out_proj): +bias +resid -> C0 (b,t,d).
// ---------------------------------------------------------------------------
template <int EPI>
__global__ __launch_bounds__(256) void gemm_mfma(const short* __restrict__ A,
                                                 const short* __restrict__ Bw,
                                                 int Kd,
                                                 const float* __restrict__ bias,
                                                 const float* __restrict__ resid,
                                                 float* __restrict__ C0,
                                                 float* __restrict__ C1) {
    __shared__ short As[4096];   // 128 rows x 32 k, fragment-ordered 16B units
    __shared__ short Bs[4096];
    int m0 = blockIdx.y * 128;
    int n0 = blockIdx.x * 128;
    int tid = threadIdx.x;
    int lane = tid & 63, wave = tid >> 6;
    int q = lane >> 4, r = lane & 15;
    int wm = wave >> 1, wn = wave & 1;

    const size_t Kb = (size_t)Kd * 2;   // row bytes
    // staging inst p covers tile rows (p*4+wave)*16 + r, col chunk q (16B)
    const char* gA0 = (const char*)A + (size_t)(m0 + wave * 16 + r) * Kb + q * 16;
    const char* gA1 = gA0 + 64 * Kb;
    const char* gB0 = (const char*)Bw + (size_t)(n0 + wave * 16 + r) * Kb + q * 16;
    const char* gB1 = gB0 + 64 * Kb;
    char* lA0 = (char*)As + wave * 1024;   // wave-uniform LDS base
    char* lA1 = lA0 + 4096;
    char* lB0 = (char*)Bs + wave * 1024;
    char* lB1 = lB0 + 4096;

    f32x4 acc[4][4] = {};

    for (int k0 = 0; k0 < Kd; k0 += 32) {
        async16(gA0, lA0); async16(gA1, lA1);
        async16(gB0, lB0); async16(gB1, lB1);
        gA0 += 64; gA1 += 64; gB0 += 64; gB1 += 64;
        __syncthreads();                 // drains vmcnt -> staged data visible
        bf16x8 af[4], bf[4];
#pragma unroll
        for (int a = 0; a < 4; a++)
            af[a] = *(const bf16x8*)&As[((wm * 4 + a) * 64 + q * 16 + r) * 8];
#pragma unroll
        for (int b = 0; b < 4; b++)
            bf[b] = *(const bf16x8*)&Bs[((wn * 4 + b) * 64 + q * 16 + r) * 8];
#pragma unroll
        for (int a = 0; a < 4; a++)
#pragma unroll
            for (int b = 0; b < 4; b++)
                acc[a][b] = __builtin_amdgcn_mfma_f32_16x16x32_bf16(
                    af[a], bf[b], acc[a][b], 0, 0, 0);
        __syncthreads();                 // protect LDS before next staging
    }

    // C/D layout: col(n) = lane&15, row(m) = (lane>>4)*4 + reg  [m89/m91]
    int bI = m0 >> 10;
#pragma unroll
    for (int a = 0; a < 4; a++) {
        int mrow = m0 + (wm * 4 + a) * 16 + q * 4;
#pragma unroll
        for (int b = 0; b < 4; b++) {
            int ncol = n0 + (wn * 4 + b) * 16 + r;
            float bb = bias[ncol];
            if (EPI == 1) {
                if (ncol < DD) {
#pragma unroll
                    for (int e = 0; e < 4; e++)
                        C0[(size_t)(mrow + e) * DD + ncol] = acc[a][b][e] + bb;
                } else {
                    int nz = ncol - DD;
                    int tt = mrow & (LL - 1);
                    float4 v = { acc[a][b][0] + bb, acc[a][b][1] + bb,
                                 acc[a][b][2] + bb, acc[a][b][3] + bb };
                    *(float4*)&C1[((size_t)(bI * DD + nz)) * LL + tt] = v;
                }
            } else {
#pragma unroll
                for (int e = 0; e < 4; e++) {
                    size_t idx = (size_t)(mrow + e) * DD + ncol;
                    C0[idx] = acc[a][b][e] + bb + resid[idx];
                }
            }
        }
    }
}

// ---------------------------------------------------------------------------
// fp32 NT GEMM (kept for dt_proj, K=48). MODE 2: softplus, transposed store.
// ---------------------------------------------------------------------------
template <int MODE>
__global__ __launch_bounds__(256) void gemm_nt(const float* __restrict__ A, int lda,
                                               const float* __restrict__ Bw, int ldb,
                                               int N, int Kd,
                                               const float* __restrict__ bias,
                                               float* __restrict__ C0,
                                               float* __restrict__ C1) {
    __shared__ __align__(16) float As[16][68];
    __shared__ __align__(16) float Bs[16][68];
    int m0 = blockIdx.y * 64;
    int n0 = blockIdx.x * 64;
    int t = threadIdx.x;
    int tx = t & 15, ty = t >> 4;
    int ar = t >> 2;
    int ak = (t & 3) * 4;
    float acc[4][4] = {};
    for (int k0 = 0; k0 < Kd; k0 += 16) {
        float4 av = *(const float4*)(A + (size_t)(m0 + ar) * lda + k0 + ak);
        int brow = n0 + ar;
        if (brow >= N) brow = N - 1;
        float4 bv = *(const float4*)(Bw + (size_t)brow * ldb + k0 + ak);
        As[ak + 0][ar] = av.x; As[ak + 1][ar] = av.y;
        As[ak + 2][ar] = av.z; As[ak + 3][ar] = av.w;
        Bs[ak + 0][ar] = bv.x; Bs[ak + 1][ar] = bv.y;
        Bs[ak + 2][ar] = bv.z; Bs[ak + 3][ar] = bv.w;
        __syncthreads();
#pragma unroll
        for (int kk = 0; kk < 16; kk++) {
            float4 a4 = *(const float4*)&As[kk][ty * 4];
            float4 b4 = *(const float4*)&Bs[kk][tx * 4];
            float aa[4] = { a4.x, a4.y, a4.z, a4.w };
            float bb[4] = { b4.x, b4.y, b4.z, b4.w };
#pragma unroll
            for (int i = 0; i < 4; i++)
#pragma unroll
                for (int j = 0; j < 4; j++) acc[i][j] += aa[i] * bb[j];
        }
        __syncthreads();
    }
    int b = m0 >> 10;
    int t0m = m0 & (LL - 1);
#pragma unroll
    for (int j = 0; j < 4; j++) {
        int n = n0 + tx * 4 + j;
        float bb = bias[n];
        float v0 = acc[0][j] + bb, v1 = acc[1][j] + bb;
        float v2 = acc[2][j] + bb, v3 = acc[3][j] + bb;
        if (MODE == 2) {
            v0 = (v0 > 20.0f) ? v0 : log1pf(__expf(v0));
            v1 = (v1 > 20.0f) ? v1 : log1pf(__expf(v1));
            v2 = (v2 > 20.0f) ? v2 : log1pf(__expf(v2));
            v3 = (v3 > 20.0f) ? v3 : log1pf(__expf(v3));
        }
        float* dst = C0 + ((size_t)(b * DD + n)) * LL + t0m + ty * 4;
        float4 v = { v0, v1, v2, v3 };
        *(float4*)dst = v;
    }
}

// ---------------------------------------------------------------------------
// fp32 TN GEMM (kept for x_proj): A K-major (b,k,t). MODE 0 plain store.
// ---------------------------------------------------------------------------
template <int MODE>
__global__ __launch_bounds__(256) void gemm_tn(const float* __restrict__ At,
                                               const float* __restrict__ Bw, int ldb,
                                               int N, int Kd,
                                               float* __restrict__ C0, int ldc) {
    __shared__ __align__(16) float As[16][68];
    __shared__ __align__(16) float Bs[16][68];
    int m0 = blockIdx.y * 64;
    int n0 = blockIdx.x * 64;
    int b = m0 >> 10;
    int t0m = m0 & (LL - 1);
    int t = threadIdx.x;
    int tx = t & 15, ty = t >> 4;
    int kk = t >> 4, tt = t & 15;
    int ar = t >> 2, ak = (t & 3) * 4;
    float acc[4][4] = {};
    for (int k0 = 0; k0 < Kd; k0 += 16) {
        float4 av = *(const float4*)(At + ((size_t)(b * Kd + k0 + kk)) * LL + t0m + tt * 4);
        int brow = n0 + ar;
        if (brow >= N) brow = N - 1;
        float4 bv = *(const float4*)(Bw + (size_t)brow * ldb + k0 + ak);
        *(float4*)&As[kk][tt * 4] = av;
        Bs[ak + 0][ar] = bv.x; Bs[ak + 1][ar] = bv.y;
        Bs[ak + 2][ar] = bv.z; Bs[ak + 3][ar] = bv.w;
        __syncthreads();
#pragma unroll
        for (int kq = 0; kq < 16; kq++) {
            float4 a4 = *(const float4*)&As[kq][ty * 4];
            float4 b4 = *(const float4*)&Bs[kq][tx * 4];
            float aa[4] = { a4.x, a4.y, a4.z, a4.w };
            float bb[4] = { b4.x, b4.y, b4.z, b4.w };
#pragma unroll
            for (int i = 0; i < 4; i++)
#pragma unroll
                for (int j = 0; j < 4; j++) acc[i][j] += aa[i] * bb[j];
        }
        __syncthreads();
    }
    int n = n0 + tx * 4;
    if (n + 3 < N) {
#pragma unroll
        for (int i = 0; i < 4; i++) {
            int m = m0 + ty * 4 + i;
            float4 v = { acc[i][0], acc[i][1], acc[i][2], acc[i][3] };
            *(float4*)(C0 + (size_t)m * ldc + n) = v;
        }
    }
}

// ---------------------------------------------------------------------------
// K3: transposing depthwise causal conv (K=4) + bias + silu -> xcT (b,d,t)
// ---------------------------------------------------------------------------
__global__ __launch_bounds__(256) void k_conv_t(const float* __restrict__ xin,
                                                const float* __restrict__ cw,
                                                const float* __restrict__ cb,
                                                float* __restrict__ xcT) {
    __shared__ float Xs[67][68];
    __shared__ float Ys[64][65];
    int b = blockIdx.y;
    int dtile = blockIdx.x % 12;
    int ttile = blockIdx.x / 12;
    int t0 = ttile * 64, d0 = dtile * 64;
    int tid = threadIdx.x;
#pragma unroll
    for (int p = 0; p < 5; p++) {
        int row = p * 16 + (tid >> 4);
        if (row < 67) {
            int col = (tid & 15) * 4;
            int tg = t0 - 3 + row;
            float4 v = { 0.f, 0.f, 0.f, 0.f };
            if (tg >= 0) v = *(const float4*)(xin + ((size_t)(b * LL + tg)) * DD + d0 + col);
            *(float4*)&Xs[row][col] = v;
        }
    }
    __syncthreads();
    int dl = tid & 63, wid = tid >> 6;
    float4 w = ((const float4*)cw)[d0 + dl];
    float bv = cb[d0 + dl];
#pragma unroll
    for (int e = 0; e < 16; e++) {
        int tl = e * 4 + wid;
        float acc = bv + Xs[tl + 0][dl] * w.x + Xs[tl + 1][dl] * w.y
                       + Xs[tl + 2][dl] * w.z + Xs[tl + 3][dl] * w.w;
        Ys[dl][tl] = silu_f(acc);
    }
    __syncthreads();
    int tl2 = tid & 63, wd = tid >> 6;
#pragma unroll
    for (int e = 0; e < 16; e++) {
        int dl2 = e * 4 + wd;
        xcT[((size_t)(b * DD + d0 + dl2)) * LL + t0 + tl2] = Ys[dl2][tl2];
    }
}

// ---------------------------------------------------------------------------
// K5: chunked selective scan (as round 3), gates in place into zT.
// ---------------------------------------------------------------------------
__global__ __launch_bounds__(256) void k_scan(const float* __restrict__ dtT,
                                              const float* __restrict__ xcT,
                                              const float* __restrict__ xdbl,
                                              const float* __restrict__ A_log,
                                              const float* __restrict__ Dp,
                                              float* __restrict__ zy) {
    int blk = blockIdx.x;
    int b = blk / DD;
    int d = blk - b * DD;
    int tid = threadIdx.x;
    int n = tid & 15;
    int c = tid >> 4;
    size_t base = (size_t)blk * LL;
    const float* dtp = dtT + base;
    const float* xcp = xcT + base;
    float* zp = zy + base;
    const float* xdp = xdbl + (size_t)b * LL * 80;
    float Acoef = -__expf(A_log[d * NNs + n]);
    int t0 = c * 64;

    float P = 1.0f, S = 0.0f;
    for (int i = 0; i < 64; i += 4) {
        float4 d4 = *(const float4*)(dtp + t0 + i);
        float4 x4 = *(const float4*)(xcp + t0 + i);
        float dv[4] = { d4.x, d4.y, d4.z, d4.w };
        float xv[4] = { x4.x, x4.y, x4.z, x4.w };
#pragma unroll
        for (int j = 0; j < 4; j++) {
            int tg = t0 + i + j;
            float Bv = xdp[tg * 80 + RR + n];
            float dA = __expf(dv[j] * Acoef);
            S = dA * S + dv[j] * Bv * xv[j];
            P *= dA;
        }
    }

    __shared__ float Pl[16][17];
    __shared__ float Sl[16][17];
    __shared__ float Hl[16][17];
    Pl[c][n] = P;
    Sl[c][n] = S;
    __syncthreads();
    if (tid < 16) {
        float h = 0.0f;
#pragma unroll
        for (int cc = 0; cc < 16; cc++) {
            Hl[cc][tid] = h;
            h = Pl[cc][tid] * h + Sl[cc][tid];
        }
    }
    __syncthreads();

    float h = Hl[c][n];
    float Dv = Dp[d];
    for (int i = 0; i < 64; i += 4) {
        float4 d4 = *(const float4*)(dtp + t0 + i);
        float4 x4 = *(const float4*)(xcp + t0 + i);
        float dv[4] = { d4.x, d4.y, d4.z, d4.w };
        float xv[4] = { x4.x, x4.y, x4.z, x4.w };
        float4 z4;
        if (n == 0) z4 = *(const float4*)(zp + t0 + i);
        float yv[4];
#pragma unroll
        for (int j = 0; j < 4; j++) {
            int tg = t0 + i + j;
            float Bv = xdp[tg * 80 + RR + n];
            float Cv = xdp[tg * 80 + RR + NNs + n];
            float dA = __expf(dv[j] * Acoef);
            h = dA * h + dv[j] * Bv * xv[j];
            float part = h * Cv;
            part += __shfl_xor(part, 8, 16);
            part += __shfl_xor(part, 4, 16);
            part += __shfl_xor(part, 2, 16);
            part += __shfl_xor(part, 1, 16);
            yv[j] = part + Dv * xv[j];
        }
        if (n == 0) {
            float4 o = { yv[0] * silu_f(z4.x), yv[1] * silu_f(z4.y),
                         yv[2] * silu_f(z4.z), yv[3] * silu_f(z4.w) };
            *(float4*)(zp + t0 + i) = o;
        }
    }
}

// ---------------------------------------------------------------------------
// K6: transpose+cvt gated y (b,d,t) fp32 -> (b,t,d) bf16 (out_proj A operand)
// ---------------------------------------------------------------------------
__global__ __launch_bounds__(256) void k_tr(const float* __restrict__ yT,
                                            short* __restrict__ yb) {
    __shared__ float T[64][65];
    int b = blockIdx.y;
    int d0 = (blockIdx.x % 12) * 64;
    int t0 = (blockIdx.x / 12) * 64;
    int tid = threadIdx.x;
    int r16 = tid >> 4, c4 = (tid & 15) * 4;
#pragma unroll
    for (int p = 0; p < 4; p++) {
        int dl = p * 16 + r16;
        float4 v = *(const float4*)&yT[((size_t)(b * DD + d0 + dl)) * LL + t0 + c4];
        T[dl][c4 + 0] = v.x; T[dl][c4 + 1] = v.y;
        T[dl][c4 + 2] = v.z; T[dl][c4 + 3] = v.w;
    }
    __syncthreads();
#pragma unroll
    for (int p = 0; p < 4; p++) {
        int tl = p * 16 + r16;
        short4 o = { f2bf(T[c4 + 0][tl]), f2bf(T[c4 + 1][tl]),
                     f2bf(T[c4 + 2][tl]), f2bf(T[c4 + 3][tl]) };
        *(short4*)&yb[((size_t)(b * LL + t0 + tl)) * DD + d0 + c4] = o;
    }
}

// ---------------------------------------------------------------------------
extern "C" void kernel_launch(void* const* d_in, const int* in_sizes, int n_in,
                              void* d_out, int out_size, void* d_ws, size_t ws_size,
                              hipStream_t stream) {
    const float* x      = (const float*)d_in[0];
    // d_in[1] batch_params, d_in[2] has_velocity: provably no effect
    const float* norm_w = (const float*)d_in[3];
    const float* in_w   = (const float*)d_in[4];
    const float* in_b   = (const float*)d_in[5];
    const float* conv_w = (const float*)d_in[6];
    const float* conv_b = (const float*)d_in[7];
    const float* xp_w   = (const float*)d_in[8];
    const float* dt_w   = (const float*)d_in[9];
    const float* dt_b   = (const float*)d_in[10];
    const float* A_log  = (const float*)d_in[11];
    const float* Dp     = (const float*)d_in[12];
    const float* out_w  = (const float*)d_in[13];
    const float* out_b  = (const float*)d_in[14];
    float* out = (float*)d_out;

    const size_t S = (size_t)BB * LL * DD;     // 6291456
    float* res   = (float*)d_ws;               // residual (fp32, S)
    float* slotA = res + S;                    // hidb (bf16) then xcT (fp32)
    float* slotB = slotA + S;                  // xin, dtT (fp32); later yb (bf16)
    float* zT    = slotB + S;                  // z (b,d,t); gated y in place
    float* xdbl  = zT + S;                     // (B*L, 80)
    short* inw_b  = (short*)(xdbl + (size_t)BB * LL * 80);   // 1536x768 bf16
    short* outw_b = inw_b + 1536 * DD;                       // 768x768 bf16

    short* hidb = (short*)slotA;
    float* xcT  = slotA;
    float* xin  = slotB;
    float* dtT  = slotB;
    short* yb   = (short*)slotB;

    const int M = BB * LL;                     // 8192

    // 0. weight conversions to bf16
    k_cvt<<<(1536 * DD / 4 + 255) / 256, 256, 0, stream>>>(in_w, inw_b, 1536 * DD / 4);
    k_cvt<<<(DD * DD / 4 + 255) / 256, 256, 0, stream>>>(out_w, outw_b, DD * DD / 4);

    // 1. pos + residual + rmsnorm (hid in bf16)
    k_pos_rms<<<M, 256, 0, stream>>>(x, norm_w, res, hidb);

    // 2. in_proj (MFMA): xz = hid @ in_w^T + b -> xin (b,t,d) | zT (b,d,t)
    gemm_mfma<1><<<dim3(1536 / 128, M / 128), 256, 0, stream>>>(
        hidb, inw_b, DD, in_b, nullptr, xin, zT);

    // 3. transposing depthwise conv + silu: xin -> xcT
    k_conv_t<<<dim3(192, BB), 256, 0, stream>>>(xin, conv_w, conv_b, xcT);

    // 4. x_proj (TN fp32): xdbl = xcT^T @ xp_w^T
    gemm_tn<0><<<dim3(2, M / 64), 256, 0, stream>>>(
        xcT, xp_w, DD, RR + 2 * NNs, DD, xdbl, 80);

    // 5. dt_proj + softplus -> dtT (b,d,t)
    gemm_nt<2><<<dim3(DD / 64, M / 64), 256, 0, stream>>>(
        xdbl, 80, dt_w, RR, DD, RR, dt_b, dtT, nullptr);

    // 6. chunked selective scan + gating (zT becomes gated y in place)
    k_scan<<<BB * DD, 256, 0, stream>>>(dtT, xcT, xdbl, A_log, Dp, zT);

    // 6.5 transpose+cvt gated y -> yb (b,t,d) bf16
    k_tr<<<dim3(192, BB), 256, 0, stream>>>(zT, yb);

    // 7. out_proj (MFMA) + bias + residual -> d_out
    gemm_mfma<3><<<dim3(DD / 128, M / 128), 256, 0, stream>>>(
        yb, outw_b, DD, out_b, res, out, nullptr);
}

// Round 5
// 415.425 us; speedup vs baseline: 3.1342x; 1.0188x over previous
//
#include <hip/hip_runtime.h>
#include <math.h>

#define BB 8
#define LL 1024
#define DD 768
#define NNs 16
#define RR 48

typedef __attribute__((ext_vector_type(8))) short bf16x8;
typedef __attribute__((ext_vector_type(4))) float f32x4;

__device__ __forceinline__ float silu_f(float v) { return v / (1.0f + __expf(-v)); }

__device__ __forceinline__ short f2bf(float f) {
    union { float f; unsigned u; } v; v.f = f;
    unsigned r = (v.u + 0x7fffu + ((v.u >> 16) & 1u)) >> 16;
    return (short)r;
}

__device__ __forceinline__ void async16(const void* g, void* l) {
    __builtin_amdgcn_global_load_lds((const __attribute__((address_space(1))) void*)g,
                                     (__attribute__((address_space(3))) void*)l,
                                     16, 0, 0);
}

// ---------------------------------------------------------------------------
// K0: fp32 -> bf16 weight conversion
// ---------------------------------------------------------------------------
__global__ __launch_bounds__(256) void k_cvt(const float* __restrict__ src,
                                             short* __restrict__ dst, int n4) {
    int i = blockIdx.x * 256 + threadIdx.x;
    if (i < n4) {
        float4 v = ((const float4*)src)[i];
        short4 o = { f2bf(v.x), f2bf(v.y), f2bf(v.z), f2bf(v.w) };
        ((short4*)dst)[i] = o;
    }
}

// ---------------------------------------------------------------------------
// K1: pos embedding (analytic; batch_params/has_velocity provably cancel) +
// residual + RMSNorm. res fp32, hidden bf16.
// ---------------------------------------------------------------------------
__global__ __launch_bounds__(256) void k_pos_rms(const float* __restrict__ x,
                                                 const float* __restrict__ norm_w,
                                                 float* __restrict__ res,
                                                 short* __restrict__ hidb) {
    int row = blockIdx.x;
    int l = row & (LL - 1);
    int d3 = l & 3;
    int w = (l >> 2) & 15;
    int h = l >> 6;
    float coord[3] = { h * (1.0f / 15.0f), w * (1.0f / 15.0f), d3 * (1.0f / 3.0f) };
    const float LOG1E4 = 9.210340371976184f;
    int t = threadIdx.x;
    float r[3];
    float s = 0.0f;
#pragma unroll
    for (int i = 0; i < 3; i++) {
        int j = t + i * 256;
        int c = j >> 8;
        int fp = j & 255;
        int f = fp & 127;
        float omega = __expf(-(f * (1.0f / 128.0f)) * LOG1E4);
        float arg = coord[c] * omega;
        float pv = (fp < 128) ? __sinf(arg) : __cosf(arg);
        float rv = x[(size_t)row * DD + j] + pv;
        r[i] = rv;
        s += rv * rv;
    }
#pragma unroll
    for (int off = 32; off; off >>= 1) s += __shfl_xor(s, off, 64);
    __shared__ float ls[4];
    if ((t & 63) == 0) ls[t >> 6] = s;
    __syncthreads();
    s = ls[0] + ls[1] + ls[2] + ls[3];
    float rs = rsqrtf(s * (1.0f / DD) + 1e-5f);
#pragma unroll
    for (int i = 0; i < 3; i++) {
        int j = t + i * 256;
        res[(size_t)row * DD + j] = r[i];
        hidb[(size_t)row * DD + j] = f2bf(r[i] * rs * norm_w[j]);
    }
}

// ---------------------------------------------------------------------------
// MFMA bf16 GEMM (NT), 128x128 tile, BK=32, 4 waves. AF32: A is fp32 and is
// converted to bf16 during LDS staging (out_proj path); else async16 staging.
// EPI 1 (in_proj): +bias; n<768 -> C0 (b,t,d); n>=768 -> C1 (b,t,d).
// EPI 3 (out_proj): +bias +resid -> C0.
// ---------------------------------------------------------------------------
template <int EPI, bool AF32>
__global__ __launch_bounds__(256) void gemm_mfma(const void* __restrict__ Ap,
                                                 const short* __restrict__ Bw,
                                                 int Kd,
                                                 const float* __restrict__ bias,
                                                 const float* __restrict__ resid,
                                                 float* __restrict__ C0,
                                                 float* __restrict__ C1) {
    __shared__ short As[4096];   // 128 rows x 32 k, fragment-ordered
    __shared__ short Bs[4096];
    int m0 = blockIdx.y * 128;
    int n0 = blockIdx.x * 128;
    int tid = threadIdx.x;
    int lane = tid & 63, wave = tid >> 6;
    int q = lane >> 4, r = lane & 15;
    int wm = wave >> 1, wn = wave & 1;

    const size_t Kb = (size_t)Kd * 2;
    const char* gB0 = (const char*)Bw + (size_t)(n0 + wave * 16 + r) * Kb + q * 16;
    const char* gB1 = gB0 + 64 * Kb;
    char* lB0 = (char*)Bs + wave * 1024;
    char* lB1 = lB0 + 4096;
    const char* gA0 = nullptr; const char* gA1 = nullptr;
    char* lA0 = nullptr; char* lA1 = nullptr;
    if (!AF32) {
        gA0 = (const char*)Ap + (size_t)(m0 + wave * 16 + r) * Kb + q * 16;
        gA1 = gA0 + 64 * Kb;
        lA0 = (char*)As + wave * 1024;
        lA1 = lA0 + 4096;
    }

    f32x4 acc[4][4] = {};

    for (int k0 = 0; k0 < Kd; k0 += 32) {
        if (AF32) {
            const float* Af = (const float*)Ap;
#pragma unroll
            for (int p = 0; p < 2; p++) {
                int m = m0 + (p * 4 + wave) * 16 + r;
                const float* src = Af + (size_t)m * Kd + k0 + q * 8;
                float4 v0 = *(const float4*)src;
                float4 v1 = *(const float4*)(src + 4);
                bf16x8 pk;
                pk[0] = f2bf(v0.x); pk[1] = f2bf(v0.y);
                pk[2] = f2bf(v0.z); pk[3] = f2bf(v0.w);
                pk[4] = f2bf(v1.x); pk[5] = f2bf(v1.y);
                pk[6] = f2bf(v1.z); pk[7] = f2bf(v1.w);
                *(bf16x8*)&As[p * 2048 + wave * 512 + lane * 8] = pk;
            }
        } else {
            async16(gA0, lA0); async16(gA1, lA1);
            gA0 += 64; gA1 += 64;
        }
        async16(gB0, lB0); async16(gB1, lB1);
        gB0 += 64; gB1 += 64;
        __syncthreads();
        bf16x8 af[4], bf[4];
#pragma unroll
        for (int a = 0; a < 4; a++)
            af[a] = *(const bf16x8*)&As[((wm * 4 + a) * 64 + q * 16 + r) * 8];
#pragma unroll
        for (int b = 0; b < 4; b++)
            bf[b] = *(const bf16x8*)&Bs[((wn * 4 + b) * 64 + q * 16 + r) * 8];
#pragma unroll
        for (int a = 0; a < 4; a++)
#pragma unroll
            for (int b = 0; b < 4; b++)
                acc[a][b] = __builtin_amdgcn_mfma_f32_16x16x32_bf16(
                    af[a], bf[b], acc[a][b], 0, 0, 0);
        __syncthreads();
    }

    // C/D layout: col(n) = lane&15, row(m) = (lane>>4)*4 + reg  [m89/m91]
#pragma unroll
    for (int a = 0; a < 4; a++) {
        int mrow = m0 + (wm * 4 + a) * 16 + q * 4;
#pragma unroll
        for (int b = 0; b < 4; b++) {
            int ncol = n0 + (wn * 4 + b) * 16 + r;
            float bb = bias[ncol];
            if (EPI == 1) {
                float* dst = (ncol < DD) ? (C0 + (size_t)mrow * DD + ncol)
                                         : (C1 + (size_t)mrow * DD + (ncol - DD));
#pragma unroll
                for (int e = 0; e < 4; e++)
                    dst[(size_t)e * DD] = acc[a][b][e] + bb;
            } else {
#pragma unroll
                for (int e = 0; e < 4; e++) {
                    size_t idx = (size_t)(mrow + e) * DD + ncol;
                    C0[idx] = acc[a][b][e] + bb + resid[idx];
                }
            }
        }
    }
}

// ---------------------------------------------------------------------------
// fp32 NT GEMM. MODE 0 (x_proj): plain store with n<N guard.
// MODE 2 (dt_proj): softplus, float4 store to (b,t,d).
// ---------------------------------------------------------------------------
template <int MODE>
__global__ __launch_bounds__(256) void gemm_nt(const float* __restrict__ A, int lda,
                                               const float* __restrict__ Bw, int ldb,
                                               int N, int Kd,
                                               const float* __restrict__ bias,
                                               float* __restrict__ C0, int ldc) {
    __shared__ __align__(16) float As[16][68];
    __shared__ __align__(16) float Bs[16][68];
    int m0 = blockIdx.y * 64;
    int n0 = blockIdx.x * 64;
    int t = threadIdx.x;
    int tx = t & 15, ty = t >> 4;
    int ar = t >> 2;
    int ak = (t & 3) * 4;
    float acc[4][4] = {};
    for (int k0 = 0; k0 < Kd; k0 += 16) {
        float4 av = *(const float4*)(A + (size_t)(m0 + ar) * lda + k0 + ak);
        int brow = n0 + ar;
        if (brow >= N) brow = N - 1;
        float4 bv = *(const float4*)(Bw + (size_t)brow * ldb + k0 + ak);
        As[ak + 0][ar] = av.x; As[ak + 1][ar] = av.y;
        As[ak + 2][ar] = av.z; As[ak + 3][ar] = av.w;
        Bs[ak + 0][ar] = bv.x; Bs[ak + 1][ar] = bv.y;
        Bs[ak + 2][ar] = bv.z; Bs[ak + 3][ar] = bv.w;
        __syncthreads();
#pragma unroll
        for (int kk = 0; kk < 16; kk++) {
            float4 a4 = *(const float4*)&As[kk][ty * 4];
            float4 b4 = *(const float4*)&Bs[kk][tx * 4];
            float aa[4] = { a4.x, a4.y, a4.z, a4.w };
            float bb[4] = { b4.x, b4.y, b4.z, b4.w };
#pragma unroll
            for (int i = 0; i < 4; i++)
#pragma unroll
                for (int j = 0; j < 4; j++) acc[i][j] += aa[i] * bb[j];
        }
        __syncthreads();
    }
    if (MODE == 0) {
#pragma unroll
        for (int i = 0; i < 4; i++) {
            int m = m0 + ty * 4 + i;
#pragma unroll
            for (int j = 0; j < 4; j++) {
                int n = n0 + tx * 4 + j;
                if (n < N) C0[(size_t)m * ldc + n] = acc[i][j];
            }
        }
    } else {
        float4 bi = *(const float4*)(bias + n0 + tx * 4);
        float bl[4] = { bi.x, bi.y, bi.z, bi.w };
#pragma unroll
        for (int i = 0; i < 4; i++) {
            int m = m0 + ty * 4 + i;
            float v[4];
#pragma unroll
            for (int j = 0; j < 4; j++) {
                float u = acc[i][j] + bl[j];
                v[j] = (u > 20.0f) ? u : log1pf(__expf(u));
            }
            float4 o = { v[0], v[1], v[2], v[3] };
            *(float4*)(C0 + (size_t)m * DD + n0 + tx * 4) = o;
        }
    }
}

// ---------------------------------------------------------------------------
// K3: depthwise causal conv (K=4) + bias + silu, (b,t,d) -> (b,t,d)
// ---------------------------------------------------------------------------
__global__ __launch_bounds__(256) void k_conv(const float* __restrict__ xin,
                                              const float* __restrict__ cw,
                                              const float* __restrict__ cb,
                                              float* __restrict__ xc) {
    size_t gid = (size_t)blockIdx.x * 256 + threadIdx.x;
    int d = (int)(gid % DD);
    int bt = (int)(gid / DD);
    int tt = bt & (LL - 1);
    float4 w = ((const float4*)cw)[d];
    const float* p = xin + (size_t)bt * DD + d;
    float acc = cb[d];
    if (tt >= 3) acc += p[-3 * DD] * w.x;
    if (tt >= 2) acc += p[-2 * DD] * w.y;
    if (tt >= 1) acc += p[-1 * DD] * w.z;
    acc += p[0] * w.w;
    xc[gid] = silu_f(acc);
}

// ---------------------------------------------------------------------------
// K5: register-state chunked selective scan.
// One thread per (b, d, chunk): 16 n-states in VGPRs, no cross-lane ops.
// Block = 32 chunks x 8 d = 256 thr; grid = (96 d-tiles, 8 b) = 3 blocks/CU.
// Phase 1: local (P[n], S[n]) over 32 t.  Phase 2: 32-step serial combine in
// LDS (thread per (d,n)).  Phase 3: rescan from h_in, y = sum_n h*C + D*xc,
// gate with silu(z), store fp32 IN PLACE into z buffer.
// B/C staged to LDS in t-groups; chunk-stride padded +8 floats (2-way banks).
// ---------------------------------------------------------------------------
__global__ __launch_bounds__(256) void k_scan(const float* __restrict__ dtf,
                                              const float* __restrict__ xc,
                                              const float* __restrict__ xdbl,
                                              const float* __restrict__ A_log,
                                              const float* __restrict__ Dp,
                                              float* __restrict__ zy) {
    __shared__ float Pl[32 * 8 * 16];      // 16 KB (becomes Hl in phase 2)
    __shared__ float Sl[32 * 8 * 16];      // 16 KB
    __shared__ float BC[32 * 136];         // 17 KB staging, padded stride
    int b = blockIdx.y;
    int d0 = blockIdx.x * 8;
    int tid = threadIdx.x;
    int dl = tid & 7;
    int c = tid >> 3;                      // chunk 0..31
    int d = d0 + dl;

    float Ac[16];
    {
        const float4* al = (const float4*)(A_log + d * NNs);
#pragma unroll
        for (int i = 0; i < 4; i++) {
            float4 v = al[i];
            Ac[i * 4 + 0] = -__expf(v.x); Ac[i * 4 + 1] = -__expf(v.y);
            Ac[i * 4 + 2] = -__expf(v.z); Ac[i * 4 + 3] = -__expf(v.w);
        }
    }
    size_t rb = ((size_t)(b * LL + c * 32)) * DD + d;
    const float* dtp = dtf + rb;
    const float* xcp = xc + rb;
    float* zp = zy + rb;
    const float* xb = xdbl + (size_t)b * LL * 80;

    // ---- Phase 1
    float P[16], S[16];
#pragma unroll
    for (int n = 0; n < 16; n++) { P[n] = 1.0f; S[n] = 0.0f; }
    for (int g = 0; g < 32; g += 8) {
        __syncthreads();
        // stage B: BC[cc*136 + tt*16 + n]
#pragma unroll
        for (int p = 0; p < 4; p++) {
            int F = tid + p * 256;         // 1024 float4s
            int cc = F >> 5;
            int rem = F & 31;
            int tt = rem >> 2;
            int n4 = rem & 3;
            float4 v = *(const float4*)(xb + (size_t)(cc * 32 + g + tt) * 80 + RR + n4 * 4);
            *(float4*)&BC[cc * 136 + tt * 16 + n4 * 4] = v;
        }
        __syncthreads();
        for (int i = 0; i < 8; i++) {
            float dtv = dtp[(size_t)(g + i) * DD];
            float xcv = xcp[(size_t)(g + i) * DD];
            float dx = dtv * xcv;
            const float* Brow = &BC[c * 136 + i * 16];
#pragma unroll
            for (int qq = 0; qq < 4; qq++) {
                float4 B4 = *(const float4*)(Brow + qq * 4);
                float bl[4] = { B4.x, B4.y, B4.z, B4.w };
#pragma unroll
                for (int j = 0; j < 4; j++) {
                    int n = qq * 4 + j;
                    float e = __expf(dtv * Ac[n]);
                    P[n] *= e;
                    S[n] = e * S[n] + dx * bl[j];
                }
            }
        }
    }
    {
        float* pw = &Pl[(c * 8 + dl) * 16];
        float* sw = &Sl[(c * 8 + dl) * 16];
#pragma unroll
        for (int qq = 0; qq < 4; qq++) {
            float4 pv = { P[qq * 4], P[qq * 4 + 1], P[qq * 4 + 2], P[qq * 4 + 3] };
            float4 sv = { S[qq * 4], S[qq * 4 + 1], S[qq * 4 + 2], S[qq * 4 + 3] };
            *(float4*)(pw + qq * 4) = pv;
            *(float4*)(sw + qq * 4) = sv;
        }
    }
    __syncthreads();
    // ---- Phase 2: serial combine, thread per (d,n), Hl overwrites Pl
    if (tid < 128) {
        int dl2 = tid >> 4, n2 = tid & 15;
        float h = 0.0f;
#pragma unroll
        for (int cc = 0; cc < 32; cc++) {
            int idx = (cc * 8 + dl2) * 16 + n2;
            float Pv = Pl[idx], Sv = Sl[idx];
            Pl[idx] = h;
            h = Pv * h + Sv;
        }
    }
    __syncthreads();
    float h[16];
    {
        const float* hr = &Pl[(c * 8 + dl) * 16];
#pragma unroll
        for (int qq = 0; qq < 4; qq++) {
            float4 v = *(const float4*)(hr + qq * 4);
            h[qq * 4] = v.x; h[qq * 4 + 1] = v.y;
            h[qq * 4 + 2] = v.z; h[qq * 4 + 3] = v.w;
        }
    }
    float Dv = Dp[d];
    // ---- Phase 3
    for (int g = 0; g < 32; g += 4) {
        __syncthreads();
        // stage B+C: BC[cc*136 + tt*32 + col]
#pragma unroll
        for (int p = 0; p < 4; p++) {
            int F = tid + p * 256;
            int cc = F >> 5;
            int rem = F & 31;
            int tt = rem >> 3;
            int c4 = rem & 7;
            float4 v = *(const float4*)(xb + (size_t)(cc * 32 + g + tt) * 80 + RR + c4 * 4);
            *(float4*)&BC[cc * 136 + tt * 32 + c4 * 4] = v;
        }
        __syncthreads();
        for (int i = 0; i < 4; i++) {
            float dtv = dtp[(size_t)(g + i) * DD];
            float xcv = xcp[(size_t)(g + i) * DD];
            float zv  = zp[(size_t)(g + i) * DD];
            float dx = dtv * xcv;
            float y = Dv * xcv;
            const float* row = &BC[c * 136 + i * 32];
#pragma unroll
            for (int qq = 0; qq < 4; qq++) {
                float4 B4 = *(const float4*)(row + qq * 4);
                float4 C4 = *(const float4*)(row + 16 + qq * 4);
                float bl[4] = { B4.x, B4.y, B4.z, B4.w };
                float cl[4] = { C4.x, C4.y, C4.z, C4.w };
#pragma unroll
                for (int j = 0; j < 4; j++) {
                    int n = qq * 4 + j;
                    float e = __expf(dtv * Ac[n]);
                    h[n] = e * h[n] + dx * bl[j];
                    y += h[n] * cl[j];
                }
            }
            zp[(size_t)(g + i) * DD] = y * silu_f(zv);
        }
    }
}

// ---------------------------------------------------------------------------
extern "C" void kernel_launch(void* const* d_in, const int* in_sizes, int n_in,
                              void* d_out, int out_size, void* d_ws, size_t ws_size,
                              hipStream_t stream) {
    const float* x      = (const float*)d_in[0];
    // d_in[1] batch_params, d_in[2] has_velocity: provably no effect
    const float* norm_w = (const float*)d_in[3];
    const float* in_w   = (const float*)d_in[4];
    const float* in_b   = (const float*)d_in[5];
    const float* conv_w = (const float*)d_in[6];
    const float* conv_b = (const float*)d_in[7];
    const float* xp_w   = (const float*)d_in[8];
    const float* dt_w   = (const float*)d_in[9];
    const float* dt_b   = (const float*)d_in[10];
    const float* A_log  = (const float*)d_in[11];
    const float* Dp     = (const float*)d_in[12];
    const float* out_w  = (const float*)d_in[13];
    const float* out_b  = (const float*)d_in[14];
    float* out = (float*)d_out;

    const size_t S = (size_t)BB * LL * DD;     // 6291456
    float* res   = (float*)d_ws;               // residual (fp32)
    float* slotA = res + S;                    // hidb (bf16) then xc (fp32)
    float* slotB = slotA + S;                  // xin then dtf (fp32)
    float* zf    = slotB + S;                  // z (b,t,d); gated y in place
    float* xdbl  = zf + S;                     // (B*L, 80)
    short* inw_b  = (short*)(xdbl + (size_t)BB * LL * 80);   // 1536x768 bf16
    short* outw_b = inw_b + 1536 * DD;                       // 768x768 bf16

    short* hidb = (short*)slotA;
    float* xc   = slotA;
    float* xin  = slotB;
    float* dtf  = slotB;

    const int M = BB * LL;                     // 8192

    // 0. weight conversions
    k_cvt<<<(1536 * DD / 4 + 255) / 256, 256, 0, stream>>>(in_w, inw_b, 1536 * DD / 4);
    k_cvt<<<(DD * DD / 4 + 255) / 256, 256, 0, stream>>>(out_w, outw_b, DD * DD / 4);

    // 1. pos + residual + rmsnorm (hidden bf16)
    k_pos_rms<<<M, 256, 0, stream>>>(x, norm_w, res, hidb);

    // 2. in_proj (MFMA): -> xin (b,t,d) | zf (b,t,d)
    gemm_mfma<1, false><<<dim3(1536 / 128, M / 128), 256, 0, stream>>>(
        hidb, inw_b, DD, in_b, nullptr, xin, zf);

    // 3. depthwise conv + silu: xin -> xc (reuses slotA; hidb dead)
    k_conv<<<(int)(S / 256), 256, 0, stream>>>(xin, conv_w, conv_b, xc);

    // 4. x_proj: xdbl = xc @ xp_w^T
    gemm_nt<0><<<dim3(2, M / 64), 256, 0, stream>>>(
        xc, DD, xp_w, DD, RR + 2 * NNs, DD, nullptr, xdbl, 80);

    // 5. dt_proj + softplus -> dtf (b,t,d) (reuses slotB; xin dead)
    gemm_nt<2><<<dim3(DD / 64, M / 64), 256, 0, stream>>>(
        xdbl, 80, dt_w, RR, DD, RR, dt_b, dtf, DD);

    // 6. register-state chunked scan + gating (zf -> gated y, in place, fp32)
    k_scan<<<dim3(DD / 8, BB), 256, 0, stream>>>(dtf, xc, xdbl, A_log, Dp, zf);

    // 7. out_proj (MFMA, fp32 A cvt-staged) + bias + residual -> d_out
    gemm_mfma<3, true><<<dim3(DD / 128, M / 128), 256, 0, stream>>>(
        zf, outw_b, DD, out_b, res, out, nullptr);
}

// Round 6
// 391.119 us; speedup vs baseline: 3.3290x; 1.0621x over previous
//
#include <hip/hip_runtime.h>
#include <math.h>

#define BB 8
#define LL 1024
#define DD 768
#define NNs 16
#define RR 48

typedef __attribute__((ext_vector_type(8))) short bf16x8;
typedef __attribute__((ext_vector_type(4))) float f32x4;

__device__ __forceinline__ float silu_f(float v) { return v / (1.0f + __expf(-v)); }

__device__ __forceinline__ short f2bf(float f) {
    union { float f; unsigned u; } v; v.f = f;
    unsigned r = (v.u + 0x7fffu + ((v.u >> 16) & 1u)) >> 16;
    return (short)r;
}

__device__ __forceinline__ void async16(const void* g, void* l) {
    __builtin_amdgcn_global_load_lds((const __attribute__((address_space(1))) void*)g,
                                     (__attribute__((address_space(3))) void*)l,
                                     16, 0, 0);
}

// ---------------------------------------------------------------------------
// K0: fp32 -> bf16 weight conversion
// ---------------------------------------------------------------------------
__global__ __launch_bounds__(256) void k_cvt(const float* __restrict__ src,
                                             short* __restrict__ dst, int n4) {
    int i = blockIdx.x * 256 + threadIdx.x;
    if (i < n4) {
        float4 v = ((const float4*)src)[i];
        short4 o = { f2bf(v.x), f2bf(v.y), f2bf(v.z), f2bf(v.w) };
        ((short4*)dst)[i] = o;
    }
}

// ---------------------------------------------------------------------------
// K1: pos embedding (analytic; batch_params/has_velocity provably cancel) +
// residual + RMSNorm. res fp32, hidden bf16.
// ---------------------------------------------------------------------------
__global__ __launch_bounds__(256) void k_pos_rms(const float* __restrict__ x,
                                                 const float* __restrict__ norm_w,
                                                 float* __restrict__ res,
                                                 short* __restrict__ hidb) {
    int row = blockIdx.x;
    int l = row & (LL - 1);
    int d3 = l & 3;
    int w = (l >> 2) & 15;
    int h = l >> 6;
    float coord[3] = { h * (1.0f / 15.0f), w * (1.0f / 15.0f), d3 * (1.0f / 3.0f) };
    const float LOG1E4 = 9.210340371976184f;
    int t = threadIdx.x;
    float r[3];
    float s = 0.0f;
#pragma unroll
    for (int i = 0; i < 3; i++) {
        int j = t + i * 256;
        int c = j >> 8;
        int fp = j & 255;
        int f = fp & 127;
        float omega = __expf(-(f * (1.0f / 128.0f)) * LOG1E4);
        float arg = coord[c] * omega;
        float pv = (fp < 128) ? __sinf(arg) : __cosf(arg);
        float rv = x[(size_t)row * DD + j] + pv;
        r[i] = rv;
        s += rv * rv;
    }
#pragma unroll
    for (int off = 32; off; off >>= 1) s += __shfl_xor(s, off, 64);
    __shared__ float ls[4];
    if ((t & 63) == 0) ls[t >> 6] = s;
    __syncthreads();
    s = ls[0] + ls[1] + ls[2] + ls[3];
    float rs = rsqrtf(s * (1.0f / DD) + 1e-5f);
#pragma unroll
    for (int i = 0; i < 3; i++) {
        int j = t + i * 256;
        res[(size_t)row * DD + j] = r[i];
        hidb[(size_t)row * DD + j] = f2bf(r[i] * rs * norm_w[j]);
    }
}

// ---------------------------------------------------------------------------
// MFMA bf16 GEMM (NT), 128x128 tile, BK=32, 4 waves. AF32: A is fp32 and is
// converted to bf16 during LDS staging (out_proj path); else async16 staging.
// EPI 1 (in_proj): +bias; n<768 -> C0 (b,t,d); n>=768 -> C1 (b,t,d).
// EPI 3 (out_proj): +bias +resid -> C0.
// ---------------------------------------------------------------------------
template <int EPI, bool AF32>
__global__ __launch_bounds__(256) void gemm_mfma(const void* __restrict__ Ap,
                                                 const short* __restrict__ Bw,
                                                 int Kd,
                                                 const float* __restrict__ bias,
                                                 const float* __restrict__ resid,
                                                 float* __restrict__ C0,
                                                 float* __restrict__ C1) {
    __shared__ short As[4096];   // 128 rows x 32 k, fragment-ordered
    __shared__ short Bs[4096];
    int m0 = blockIdx.y * 128;
    int n0 = blockIdx.x * 128;
    int tid = threadIdx.x;
    int lane = tid & 63, wave = tid >> 6;
    int q = lane >> 4, r = lane & 15;
    int wm = wave >> 1, wn = wave & 1;

    const size_t Kb = (size_t)Kd * 2;
    const char* gB0 = (const char*)Bw + (size_t)(n0 + wave * 16 + r) * Kb + q * 16;
    const char* gB1 = gB0 + 64 * Kb;
    char* lB0 = (char*)Bs + wave * 1024;
    char* lB1 = lB0 + 4096;
    const char* gA0 = nullptr; const char* gA1 = nullptr;
    char* lA0 = nullptr; char* lA1 = nullptr;
    if (!AF32) {
        gA0 = (const char*)Ap + (size_t)(m0 + wave * 16 + r) * Kb + q * 16;
        gA1 = gA0 + 64 * Kb;
        lA0 = (char*)As + wave * 1024;
        lA1 = lA0 + 4096;
    }

    f32x4 acc[4][4] = {};

    for (int k0 = 0; k0 < Kd; k0 += 32) {
        if (AF32) {
            const float* Af = (const float*)Ap;
#pragma unroll
            for (int p = 0; p < 2; p++) {
                int m = m0 + (p * 4 + wave) * 16 + r;
                const float* src = Af + (size_t)m * Kd + k0 + q * 8;
                float4 v0 = *(const float4*)src;
                float4 v1 = *(const float4*)(src + 4);
                bf16x8 pk;
                pk[0] = f2bf(v0.x); pk[1] = f2bf(v0.y);
                pk[2] = f2bf(v0.z); pk[3] = f2bf(v0.w);
                pk[4] = f2bf(v1.x); pk[5] = f2bf(v1.y);
                pk[6] = f2bf(v1.z); pk[7] = f2bf(v1.w);
                *(bf16x8*)&As[p * 2048 + wave * 512 + lane * 8] = pk;
            }
        } else {
            async16(gA0, lA0); async16(gA1, lA1);
            gA0 += 64; gA1 += 64;
        }
        async16(gB0, lB0); async16(gB1, lB1);
        gB0 += 64; gB1 += 64;
        __syncthreads();
        bf16x8 af[4], bf[4];
#pragma unroll
        for (int a = 0; a < 4; a++)
            af[a] = *(const bf16x8*)&As[((wm * 4 + a) * 64 + q * 16 + r) * 8];
#pragma unroll
        for (int b = 0; b < 4; b++)
            bf[b] = *(const bf16x8*)&Bs[((wn * 4 + b) * 64 + q * 16 + r) * 8];
#pragma unroll
        for (int a = 0; a < 4; a++)
#pragma unroll
            for (int b = 0; b < 4; b++)
                acc[a][b] = __builtin_amdgcn_mfma_f32_16x16x32_bf16(
                    af[a], bf[b], acc[a][b], 0, 0, 0);
        __syncthreads();
    }

    // C/D layout: col(n) = lane&15, row(m) = (lane>>4)*4 + reg  [m89/m91]
#pragma unroll
    for (int a = 0; a < 4; a++) {
        int mrow = m0 + (wm * 4 + a) * 16 + q * 4;
#pragma unroll
        for (int b = 0; b < 4; b++) {
            int ncol = n0 + (wn * 4 + b) * 16 + r;
            float bb = bias[ncol];
            if (EPI == 1) {
                float* dst = (ncol < DD) ? (C0 + (size_t)mrow * DD + ncol)
                                         : (C1 + (size_t)mrow * DD + (ncol - DD));
#pragma unroll
                for (int e = 0; e < 4; e++)
                    dst[(size_t)e * DD] = acc[a][b][e] + bb;
            } else {
#pragma unroll
                for (int e = 0; e < 4; e++) {
                    size_t idx = (size_t)(mrow + e) * DD + ncol;
                    C0[idx] = acc[a][b][e] + bb + resid[idx];
                }
            }
        }
    }
}

// ---------------------------------------------------------------------------
// fp32 NT GEMM. MODE 0 (x_proj): plain store with n<N guard.
// MODE 2 (dt_proj): softplus, float4 store to (b,t,d).
// ---------------------------------------------------------------------------
template <int MODE>
__global__ __launch_bounds__(256) void gemm_nt(const float* __restrict__ A, int lda,
                                               const float* __restrict__ Bw, int ldb,
                                               int N, int Kd,
                                               const float* __restrict__ bias,
                                               float* __restrict__ C0, int ldc) {
    __shared__ __align__(16) float As[16][68];
    __shared__ __align__(16) float Bs[16][68];
    int m0 = blockIdx.y * 64;
    int n0 = blockIdx.x * 64;
    int t = threadIdx.x;
    int tx = t & 15, ty = t >> 4;
    int ar = t >> 2;
    int ak = (t & 3) * 4;
    float acc[4][4] = {};
    for (int k0 = 0; k0 < Kd; k0 += 16) {
        float4 av = *(const float4*)(A + (size_t)(m0 + ar) * lda + k0 + ak);
        int brow = n0 + ar;
        if (brow >= N) brow = N - 1;
        float4 bv = *(const float4*)(Bw + (size_t)brow * ldb + k0 + ak);
        As[ak + 0][ar] = av.x; As[ak + 1][ar] = av.y;
        As[ak + 2][ar] = av.z; As[ak + 3][ar] = av.w;
        Bs[ak + 0][ar] = bv.x; Bs[ak + 1][ar] = bv.y;
        Bs[ak + 2][ar] = bv.z; Bs[ak + 3][ar] = bv.w;
        __syncthreads();
#pragma unroll
        for (int kk = 0; kk < 16; kk++) {
            float4 a4 = *(const float4*)&As[kk][ty * 4];
            float4 b4 = *(const float4*)&Bs[kk][tx * 4];
            float aa[4] = { a4.x, a4.y, a4.z, a4.w };
            float bb[4] = { b4.x, b4.y, b4.z, b4.w };
#pragma unroll
            for (int i = 0; i < 4; i++)
#pragma unroll
                for (int j = 0; j < 4; j++) acc[i][j] += aa[i] * bb[j];
        }
        __syncthreads();
    }
    if (MODE == 0) {
#pragma unroll
        for (int i = 0; i < 4; i++) {
            int m = m0 + ty * 4 + i;
#pragma unroll
            for (int j = 0; j < 4; j++) {
                int n = n0 + tx * 4 + j;
                if (n < N) C0[(size_t)m * ldc + n] = acc[i][j];
            }
        }
    } else {
        float4 bi = *(const float4*)(bias + n0 + tx * 4);
        float bl[4] = { bi.x, bi.y, bi.z, bi.w };
#pragma unroll
        for (int i = 0; i < 4; i++) {
            int m = m0 + ty * 4 + i;
            float v[4];
#pragma unroll
            for (int j = 0; j < 4; j++) {
                float u = acc[i][j] + bl[j];
                v[j] = (u > 20.0f) ? u : log1pf(__expf(u));
            }
            float4 o = { v[0], v[1], v[2], v[3] };
            *(float4*)(C0 + (size_t)m * DD + n0 + tx * 4) = o;
        }
    }
}

// ---------------------------------------------------------------------------
// K3: depthwise causal conv (K=4) + bias + silu, (b,t,d) -> (b,t,d)
// ---------------------------------------------------------------------------
__global__ __launch_bounds__(256) void k_conv(const float* __restrict__ xin,
                                              const float* __restrict__ cw,
                                              const float* __restrict__ cb,
                                              float* __restrict__ xc) {
    size_t gid = (size_t)blockIdx.x * 256 + threadIdx.x;
    int d = (int)(gid % DD);
    int bt = (int)(gid / DD);
    int tt = bt & (LL - 1);
    float4 w = ((const float4*)cw)[d];
    const float* p = xin + (size_t)bt * DD + d;
    float acc = cb[d];
    if (tt >= 3) acc += p[-3 * DD] * w.x;
    if (tt >= 2) acc += p[-2 * DD] * w.y;
    if (tt >= 1) acc += p[-1 * DD] * w.z;
    acc += p[0] * w.w;
    xc[gid] = silu_f(acc);
}

// ---------------------------------------------------------------------------
// K5: register-state chunked selective scan, v3.
// One thread per (b, d, chunk): 16 n-states in VGPRs, no cross-lane ops.
// Block = 16 d x 16 chunks (of 64 t) = 256 thr -> d-footprint 16 = full 64 B
// lines on every dt/xc/z access (fixes the round-5 2x overfetch).
// Grid = (48 d-tiles, 8 b) = 384 blocks; 2 blocks co-resident on half the CUs
// (LDS 32 KB, VGPR ~130 -> 12 waves/CU capacity).
// B/C read directly from global: xdbl is 2.6 MB, L2-resident; 16 d-lanes
// share each address (HW broadcast).
// Phase 1: per-chunk (P[n], S[n]).  Phase 2: 16-step serial combine in LDS
// (thread per (d,n)).  Phase 3: rescan from h_in, y = sum_n h*C + D*xc,
// gate with silu(z), store fp32 IN PLACE into z buffer.
// ---------------------------------------------------------------------------
__global__ __launch_bounds__(256) void k_scan(const float* __restrict__ dtf,
                                              const float* __restrict__ xc,
                                              const float* __restrict__ xdbl,
                                              const float* __restrict__ A_log,
                                              const float* __restrict__ Dp,
                                              float* __restrict__ zy) {
    __shared__ float Pl[16 * 16 * 16];     // [c][d][n] 16 KB; becomes H
    __shared__ float Sl[16 * 16 * 16];     // 16 KB
    int b = blockIdx.y;
    int d0 = blockIdx.x * 16;
    int tid = threadIdx.x;
    int dl = tid & 15;
    int c = tid >> 4;                      // chunk 0..15 (64 t each)
    int d = d0 + dl;

    float Ac[16];
    {
        const float4* al = (const float4*)(A_log + d * NNs);
#pragma unroll
        for (int i = 0; i < 4; i++) {
            float4 v = al[i];
            Ac[i * 4 + 0] = -__expf(v.x); Ac[i * 4 + 1] = -__expf(v.y);
            Ac[i * 4 + 2] = -__expf(v.z); Ac[i * 4 + 3] = -__expf(v.w);
        }
    }
    size_t rb = ((size_t)(b * LL + c * 64)) * DD + d;
    const float* dtp = dtf + rb;
    const float* xcp = xc + rb;
    float* zp = zy + rb;
    const float* xrow = xdbl + ((size_t)(b * LL + c * 64)) * 80 + RR;

    // ---- Phase 1: local scan from zero state
    float P[16], S[16];
#pragma unroll
    for (int n = 0; n < 16; n++) { P[n] = 1.0f; S[n] = 0.0f; }
    for (int i = 0; i < 64; i++) {
        float dtv = dtp[(size_t)i * DD];
        float xcv = xcp[(size_t)i * DD];
        float dx = dtv * xcv;
        const float* Br = xrow + i * 80;
#pragma unroll
        for (int qq = 0; qq < 4; qq++) {
            float4 B4 = *(const float4*)(Br + qq * 4);
            float bl[4] = { B4.x, B4.y, B4.z, B4.w };
#pragma unroll
            for (int j = 0; j < 4; j++) {
                int n = qq * 4 + j;
                float e = __expf(dtv * Ac[n]);
                P[n] *= e;
                S[n] = e * S[n] + dx * bl[j];
            }
        }
    }
    {
        float* pw = &Pl[(c * 16 + dl) * 16];
        float* sw = &Sl[(c * 16 + dl) * 16];
#pragma unroll
        for (int qq = 0; qq < 4; qq++) {
            float4 pv = { P[qq * 4], P[qq * 4 + 1], P[qq * 4 + 2], P[qq * 4 + 3] };
            float4 sv = { S[qq * 4], S[qq * 4 + 1], S[qq * 4 + 2], S[qq * 4 + 3] };
            *(float4*)(pw + qq * 4) = pv;
            *(float4*)(sw + qq * 4) = sv;
        }
    }
    __syncthreads();
    // ---- Phase 2: serial combine, thread per (d,n); H overwrites Pl
    {
        int d2 = tid >> 4, n2 = tid & 15;
        float hh = 0.0f;
#pragma unroll
        for (int cc = 0; cc < 16; cc++) {
            int idx = (cc * 16 + d2) * 16 + n2;
            float Pv = Pl[idx], Sv = Sl[idx];
            Pl[idx] = hh;
            hh = Pv * hh + Sv;
        }
    }
    __syncthreads();
    float h[16];
    {
        const float* hr = &Pl[(c * 16 + dl) * 16];
#pragma unroll
        for (int qq = 0; qq < 4; qq++) {
            float4 v = *(const float4*)(hr + qq * 4);
            h[qq * 4] = v.x; h[qq * 4 + 1] = v.y;
            h[qq * 4 + 2] = v.z; h[qq * 4 + 3] = v.w;
        }
    }
    float Dv = Dp[d];
    // ---- Phase 3: rescan from h_in, gate, write in place
    for (int i = 0; i < 64; i++) {
        float dtv = dtp[(size_t)i * DD];
        float xcv = xcp[(size_t)i * DD];
        float zv  = zp[(size_t)i * DD];
        float dx = dtv * xcv;
        float y = Dv * xcv;
        const float* Br = xrow + i * 80;
#pragma unroll
        for (int qq = 0; qq < 4; qq++) {
            float4 B4 = *(const float4*)(Br + qq * 4);
            float4 C4 = *(const float4*)(Br + 16 + qq * 4);
            float bl[4] = { B4.x, B4.y, B4.z, B4.w };
            float cl[4] = { C4.x, C4.y, C4.z, C4.w };
#pragma unroll
            for (int j = 0; j < 4; j++) {
                int n = qq * 4 + j;
                float e = __expf(dtv * Ac[n]);
                h[n] = e * h[n] + dx * bl[j];
                y += h[n] * cl[j];
            }
        }
        zp[(size_t)i * DD] = y * silu_f(zv);
    }
}

// ---------------------------------------------------------------------------
extern "C" void kernel_launch(void* const* d_in, const int* in_sizes, int n_in,
                              void* d_out, int out_size, void* d_ws, size_t ws_size,
                              hipStream_t stream) {
    const float* x      = (const float*)d_in[0];
    // d_in[1] batch_params, d_in[2] has_velocity: provably no effect
    const float* norm_w = (const float*)d_in[3];
    const float* in_w   = (const float*)d_in[4];
    const float* in_b   = (const float*)d_in[5];
    const float* conv_w = (const float*)d_in[6];
    const float* conv_b = (const float*)d_in[7];
    const float* xp_w   = (const float*)d_in[8];
    const float* dt_w   = (const float*)d_in[9];
    const float* dt_b   = (const float*)d_in[10];
    const float* A_log  = (const float*)d_in[11];
    const float* Dp     = (const float*)d_in[12];
    const float* out_w  = (const float*)d_in[13];
    const float* out_b  = (const float*)d_in[14];
    float* out = (float*)d_out;

    const size_t S = (size_t)BB * LL * DD;     // 6291456
    float* res   = (float*)d_ws;               // residual (fp32)
    float* slotA = res + S;                    // hidb (bf16) then xc (fp32)
    float* slotB = slotA + S;                  // xin then dtf (fp32)
    float* zf    = slotB + S;                  // z (b,t,d); gated y in place
    float* xdbl  = zf + S;                     // (B*L, 80)
    short* inw_b  = (short*)(xdbl + (size_t)BB * LL * 80);   // 1536x768 bf16
    short* outw_b = inw_b + 1536 * DD;                       // 768x768 bf16

    short* hidb = (short*)slotA;
    float* xc   = slotA;
    float* xin  = slotB;
    float* dtf  = slotB;

    const int M = BB * LL;                     // 8192

    // 0. weight conversions
    k_cvt<<<(1536 * DD / 4 + 255) / 256, 256, 0, stream>>>(in_w, inw_b, 1536 * DD / 4);
    k_cvt<<<(DD * DD / 4 + 255) / 256, 256, 0, stream>>>(out_w, outw_b, DD * DD / 4);

    // 1. pos + residual + rmsnorm (hidden bf16)
    k_pos_rms<<<M, 256, 0, stream>>>(x, norm_w, res, hidb);

    // 2. in_proj (MFMA): -> xin (b,t,d) | zf (b,t,d)
    gemm_mfma<1, false><<<dim3(1536 / 128, M / 128), 256, 0, stream>>>(
        hidb, inw_b, DD, in_b, nullptr, xin, zf);

    // 3. depthwise conv + silu: xin -> xc (reuses slotA; hidb dead)
    k_conv<<<(int)(S / 256), 256, 0, stream>>>(xin, conv_w, conv_b, xc);

    // 4. x_proj: xdbl = xc @ xp_w^T
    gemm_nt<0><<<dim3(2, M / 64), 256, 0, stream>>>(
        xc, DD, xp_w, DD, RR + 2 * NNs, DD, nullptr, xdbl, 80);

    // 5. dt_proj + softplus -> dtf (b,t,d) (reuses slotB; xin dead)
    gemm_nt<2><<<dim3(DD / 64, M / 64), 256, 0, stream>>>(
        xdbl, 80, dt_w, RR, DD, RR, dt_b, dtf, DD);

    // 6. register-state chunked scan + gating (zf -> gated y, in place, fp32)
    k_scan<<<dim3(DD / 16, BB), 256, 0, stream>>>(dtf, xc, xdbl, A_log, Dp, zf);

    // 7. out_proj (MFMA, fp32 A cvt-staged) + bias + residual -> d_out
    gemm_mfma<3, true><<<dim3(DD / 128, M / 128), 256, 0, stream>>>(
        zf, outw_b, DD, out_b, res, out, nullptr);
}